// Round 1
// baseline (2480.872 us; speedup 1.0000x reference)
//
#include <hip/hip_runtime.h>

#define EPSV 1e-5f

// ---------------------------------------------------------------------------
// Kernel 1: qkv = w_qkv(768x256) @ x[b](256x4096), scattered to Q/K/V [bh][n][32]
// ---------------------------------------------------------------------------
__global__ __launch_bounds__(256) void qkv_gemm_kernel(
    const float* __restrict__ x, const float* __restrict__ w,
    float* __restrict__ Q, float* __restrict__ K, float* __restrict__ V) {
  __shared__ float As[16][68];   // [c][o], padded row=272B (16B aligned)
  __shared__ float Bs[16][64];   // [c][n]
  const int nB = blockIdx.x * 64;
  const int oB = blockIdx.y * 64;
  const int b  = blockIdx.z;
  const int tid = threadIdx.x;
  const int tx = tid & 15, ty = tid >> 4;
  const float* xb = x + (size_t)b * 256 * 4096;
  float acc[4][4] = {};
  for (int c0 = 0; c0 < 256; c0 += 16) {
    {
      int o = tid >> 2, cc = (tid & 3) * 4;
      float4 a4 = *(const float4*)(w + (size_t)(oB + o) * 256 + c0 + cc);
      As[cc + 0][o] = a4.x; As[cc + 1][o] = a4.y;
      As[cc + 2][o] = a4.z; As[cc + 3][o] = a4.w;
    }
    {
      int cc = tid >> 4, nn = (tid & 15) * 4;
      *(float4*)&Bs[cc][nn] = *(const float4*)(xb + (size_t)(c0 + cc) * 4096 + nB + nn);
    }
    __syncthreads();
#pragma unroll
    for (int kk = 0; kk < 16; kk++) {
      float a[4], bb[4];
      *(float4*)a  = *(const float4*)&As[kk][ty * 4];
      *(float4*)bb = *(const float4*)&Bs[kk][tx * 4];
#pragma unroll
      for (int i = 0; i < 4; i++)
#pragma unroll
        for (int j = 0; j < 4; j++) acc[i][j] += a[i] * bb[j];
    }
    __syncthreads();
  }
#pragma unroll
  for (int i = 0; i < 4; i++) {
    int o = oB + ty * 4 + i;
    int which = o >> 8, h = (o >> 5) & 7, d = o & 31;
    float* base = (which == 0 ? Q : (which == 1 ? K : V));
    float* dst = base + ((size_t)((b * 8 + h) * 4096)) * 32 + d;
#pragma unroll
    for (int j = 0; j < 4; j++) {
      int n = nB + tx * 4 + j;
      dst[(size_t)n * 32] = acc[i][j];
    }
  }
}

// ---------------------------------------------------------------------------
// Kernel 2: conv3x3 + BN  -> localOut [b][c][n]
// grid: (y=64, oTile=4, b=2); block computes 64 o x 64 x for one row y
// ---------------------------------------------------------------------------
__global__ __launch_bounds__(256) void conv3x3_bn_kernel(
    const float* __restrict__ x, const float* __restrict__ w,
    const float* __restrict__ g, const float* __restrict__ be,
    const float* __restrict__ mu, const float* __restrict__ var,
    float* __restrict__ out) {
  const int y  = blockIdx.x;
  const int oB = blockIdx.y * 64;
  const int b  = blockIdx.z;
  __shared__ float Xs[8][3][68];   // [c][row][x+1], x index 0..65
  __shared__ float Ws[8][64][9];   // [c][o][tap]
  const int tid = threadIdx.x;
  const int tx = tid & 15, ty = tid >> 4;
  const float* xb = x + (size_t)b * 256 * 4096;
  float acc[4][4] = {};
  for (int c0 = 0; c0 < 256; c0 += 8) {
    for (int idx = tid; idx < 8 * 3 * 66; idx += 256) {
      int c = idx / 198;
      int rem = idx - c * 198;
      int r = rem / 66;
      int xx = rem - r * 66;
      int ys = y + r - 1, xs = xx - 1;
      float v = 0.f;
      if (ys >= 0 && ys < 64 && xs >= 0 && xs < 64)
        v = xb[(size_t)(c0 + c) * 4096 + ys * 64 + xs];
      Xs[c][r][xx] = v;
    }
    for (int idx = tid; idx < 64 * 8 * 9; idx += 256) {
      int o = idx / 72;
      int rem = idx - o * 72;
      int c = rem / 9;
      int t = rem - c * 9;
      Ws[c][o][t] = w[((size_t)(oB + o) * 256 + c0 + c) * 9 + t];
    }
    __syncthreads();
#pragma unroll
    for (int c = 0; c < 8; c++) {
      float xr[3][6];
#pragma unroll
      for (int r = 0; r < 3; r++)
#pragma unroll
        for (int j = 0; j < 6; j++) xr[r][j] = Xs[c][r][tx * 4 + j];
#pragma unroll
      for (int i = 0; i < 4; i++) {
        const float* wp = &Ws[c][ty * 4 + i][0];
        float wv[9];
#pragma unroll
        for (int t = 0; t < 9; t++) wv[t] = wp[t];
#pragma unroll
        for (int j = 0; j < 4; j++) {
          float s = acc[i][j];
          s += wv[0] * xr[0][j + 0] + wv[1] * xr[0][j + 1] + wv[2] * xr[0][j + 2];
          s += wv[3] * xr[1][j + 0] + wv[4] * xr[1][j + 1] + wv[5] * xr[1][j + 2];
          s += wv[6] * xr[2][j + 0] + wv[7] * xr[2][j + 1] + wv[8] * xr[2][j + 2];
          acc[i][j] = s;
        }
      }
    }
    __syncthreads();
  }
#pragma unroll
  for (int i = 0; i < 4; i++) {
    int o = oB + ty * 4 + i;
    float inv = g[o] * rsqrtf(var[o] + EPSV);
    float sh  = be[o] - mu[o] * inv;
    float4 r;
    r.x = acc[i][0] * inv + sh;
    r.y = acc[i][1] * inv + sh;
    r.z = acc[i][2] * inv + sh;
    r.w = acc[i][3] * inv + sh;
    *(float4*)(out + ((size_t)(b * 256 + o)) * 4096 + y * 64 + tx * 4) = r;
  }
}

// ---------------------------------------------------------------------------
// Kernel 3: flash attention, one query per thread.
// Q/K/V: [bh][n][32]; out: attnOut [b][c][n], c = h*32+d
// grid: (qTile=16, bh=16), block 256
// ---------------------------------------------------------------------------
__global__ __launch_bounds__(256) void flash_attn_kernel(
    const float* __restrict__ Q, const float* __restrict__ K,
    const float* __restrict__ V, float* __restrict__ out) {
  __shared__ float Ks[32][32];
  __shared__ float Vs[32][32];
  const int bh = blockIdx.y;
  const int n  = blockIdx.x * 256 + threadIdx.x;
  const float scale = 0.17677669529663687f;  // 1/sqrt(32)
  float q[32];
  {
    const float* Qp = Q + ((size_t)bh * 4096 + n) * 32;
#pragma unroll
    for (int d = 0; d < 32; d += 4) *(float4*)&q[d] = *(const float4*)&Qp[d];
#pragma unroll
    for (int d = 0; d < 32; d++) q[d] *= scale;
  }
  float m = -1e30f, l = 0.f;
  float o[32] = {};
  const float* Kb = K + (size_t)bh * 4096 * 32;
  const float* Vb = V + (size_t)bh * 4096 * 32;
  const int r  = threadIdx.x >> 3;
  const int cc = (threadIdx.x & 7) * 4;
  for (int t = 0; t < 4096; t += 32) {
    __syncthreads();
    *(float4*)&Ks[r][cc] = *(const float4*)&Kb[(size_t)(t + r) * 32 + cc];
    *(float4*)&Vs[r][cc] = *(const float4*)&Vb[(size_t)(t + r) * 32 + cc];
    __syncthreads();
    float s[32];
#pragma unroll
    for (int j = 0; j < 32; j++) {
      const float4* kr = (const float4*)&Ks[j][0];
      float a0 = 0.f, a1 = 0.f, a2 = 0.f, a3 = 0.f;
#pragma unroll
      for (int dd = 0; dd < 8; dd++) {
        float4 kv = kr[dd];
        a0 += q[dd * 4 + 0] * kv.x;
        a1 += q[dd * 4 + 1] * kv.y;
        a2 += q[dd * 4 + 2] * kv.z;
        a3 += q[dd * 4 + 3] * kv.w;
      }
      s[j] = (a0 + a1) + (a2 + a3);
    }
    float mt = m;
#pragma unroll
    for (int j = 0; j < 32; j++) mt = fmaxf(mt, s[j]);
    float alpha = __expf(m - mt);
    m = mt;
    l *= alpha;
#pragma unroll
    for (int d = 0; d < 32; d++) o[d] *= alpha;
#pragma unroll
    for (int j = 0; j < 32; j++) {
      float p = __expf(s[j] - mt);
      l += p;
      const float4* vr = (const float4*)&Vs[j][0];
#pragma unroll
      for (int dd = 0; dd < 8; dd++) {
        float4 vv = vr[dd];
        o[dd * 4 + 0] += p * vv.x;
        o[dd * 4 + 1] += p * vv.y;
        o[dd * 4 + 2] += p * vv.z;
        o[dd * 4 + 3] += p * vv.w;
      }
    }
  }
  const float rl = 1.0f / l;
  const int b = bh >> 3, h = bh & 7;
  float* ob = out + ((size_t)(b * 256 + h * 32)) * 4096 + n;
#pragma unroll
  for (int d = 0; d < 32; d++) ob[(size_t)d * 4096] = o[d] * rl;
}

// ---------------------------------------------------------------------------
// Kernel 4: Y = BN(w_proj(256x256) @ (attnOut + localOut)) -> d_out [b][c][n]
// ---------------------------------------------------------------------------
__global__ __launch_bounds__(256) void proj_gemm_bn_kernel(
    const float* __restrict__ S1, const float* __restrict__ S2,
    const float* __restrict__ w,
    const float* __restrict__ g, const float* __restrict__ be,
    const float* __restrict__ mu, const float* __restrict__ var,
    float* __restrict__ out) {
  __shared__ float As[16][68];
  __shared__ float Bs[16][64];
  const int nB = blockIdx.x * 64;
  const int oB = blockIdx.y * 64;
  const int b  = blockIdx.z;
  const int tid = threadIdx.x;
  const int tx = tid & 15, ty = tid >> 4;
  const float* s1b = S1 + (size_t)b * 256 * 4096;
  const float* s2b = S2 + (size_t)b * 256 * 4096;
  float acc[4][4] = {};
  for (int c0 = 0; c0 < 256; c0 += 16) {
    {
      int o = tid >> 2, cc = (tid & 3) * 4;
      float4 a4 = *(const float4*)(w + (size_t)(oB + o) * 256 + c0 + cc);
      As[cc + 0][o] = a4.x; As[cc + 1][o] = a4.y;
      As[cc + 2][o] = a4.z; As[cc + 3][o] = a4.w;
    }
    {
      int cc = tid >> 4, nn = (tid & 15) * 4;
      size_t off = (size_t)(c0 + cc) * 4096 + nB + nn;
      float4 b1 = *(const float4*)(s1b + off);
      float4 b2 = *(const float4*)(s2b + off);
      float4 bs;
      bs.x = b1.x + b2.x; bs.y = b1.y + b2.y;
      bs.z = b1.z + b2.z; bs.w = b1.w + b2.w;
      *(float4*)&Bs[cc][nn] = bs;
    }
    __syncthreads();
#pragma unroll
    for (int kk = 0; kk < 16; kk++) {
      float a[4], bb[4];
      *(float4*)a  = *(const float4*)&As[kk][ty * 4];
      *(float4*)bb = *(const float4*)&Bs[kk][tx * 4];
#pragma unroll
      for (int i = 0; i < 4; i++)
#pragma unroll
        for (int j = 0; j < 4; j++) acc[i][j] += a[i] * bb[j];
    }
    __syncthreads();
  }
#pragma unroll
  for (int i = 0; i < 4; i++) {
    int o = oB + ty * 4 + i;
    float inv = g[o] * rsqrtf(var[o] + EPSV);
    float sh  = be[o] - mu[o] * inv;
    float4 r;
    r.x = acc[i][0] * inv + sh;
    r.y = acc[i][1] * inv + sh;
    r.z = acc[i][2] * inv + sh;
    r.w = acc[i][3] * inv + sh;
    *(float4*)(out + ((size_t)(b * 256 + o)) * 4096 + nB + tx * 4) = r;
  }
}

extern "C" void kernel_launch(void* const* d_in, const int* in_sizes, int n_in,
                              void* d_out, int out_size, void* d_ws, size_t ws_size,
                              hipStream_t stream) {
  (void)in_sizes; (void)n_in; (void)out_size; (void)ws_size;
  const float* x       = (const float*)d_in[0];
  const float* w_qkv   = (const float*)d_in[1];
  const float* w_local = (const float*)d_in[2];
  const float* lg = (const float*)d_in[3];
  const float* lb = (const float*)d_in[4];
  const float* lm = (const float*)d_in[5];
  const float* lv = (const float*)d_in[6];
  const float* w_proj  = (const float*)d_in[7];
  const float* pg = (const float*)d_in[8];
  const float* pb = (const float*)d_in[9];
  const float* pm = (const float*)d_in[10];
  const float* pvr = (const float*)d_in[11];
  float* out = (float*)d_out;

  float* ws = (float*)d_ws;
  float* Q        = ws;                   // 16*4096*32 = 2M floats
  float* K        = Q + 2097152;
  float* V        = K + 2097152;
  float* attnOut  = V + 2097152;          // [b][c][n] 2M floats
  float* localOut = attnOut + 2097152;    // [b][c][n] 2M floats

  hipLaunchKernelGGL(conv3x3_bn_kernel, dim3(64, 4, 2), dim3(256), 0, stream,
                     x, w_local, lg, lb, lm, lv, localOut);
  hipLaunchKernelGGL(qkv_gemm_kernel, dim3(64, 12, 2), dim3(256), 0, stream,
                     x, w_qkv, Q, K, V);
  hipLaunchKernelGGL(flash_attn_kernel, dim3(16, 16), dim3(256), 0, stream,
                     Q, K, V, attnOut);
  hipLaunchKernelGGL(proj_gemm_bn_kernel, dim3(64, 4, 2), dim3(256), 0, stream,
                     attnOut, localOut, w_proj, pg, pb, pm, pvr, out);
}

// Round 2
// 795.910 us; speedup vs baseline: 3.1170x; 3.1170x over previous
//
#include <hip/hip_runtime.h>

#define EPSV 1e-5f

typedef unsigned short u16;
typedef unsigned int u32;
typedef __attribute__((ext_vector_type(8))) short bf16x8;
typedef __attribute__((ext_vector_type(4))) float f32x4;

__device__ __forceinline__ u16 f2bf(float f) {
  u32 u = __float_as_uint(f);
  u32 r = (u + 0x7FFFu + ((u >> 16) & 1u)) >> 16;
  return (u16)r;
}

// ---------------------------------------------------------------------------
// Kernel 1: qkv = w_qkv(768x256) @ x[b](256x4096)
// outputs: Qg/Kg bf16 [bh][n][32] (Q pre-scaled by scale*log2e), Vt bf16 [bh][d][4096]
// ---------------------------------------------------------------------------
__global__ __launch_bounds__(256) void qkv_gemm_kernel(
    const float* __restrict__ x, const float* __restrict__ w,
    u16* __restrict__ Qg, u16* __restrict__ Kg, u16* __restrict__ Vtg) {
  __shared__ float As[16][68];
  __shared__ float Bs[16][64];
  const int nB = blockIdx.x * 64;
  const int oB = blockIdx.y * 64;
  const int b  = blockIdx.z;
  const int tid = threadIdx.x;
  const int tx = tid & 15, ty = tid >> 4;
  const float* xb = x + (size_t)b * 256 * 4096;
  float acc[4][4] = {};
  for (int c0 = 0; c0 < 256; c0 += 16) {
    {
      int o = tid >> 2, cc = (tid & 3) * 4;
      float4 a4 = *(const float4*)(w + (size_t)(oB + o) * 256 + c0 + cc);
      As[cc + 0][o] = a4.x; As[cc + 1][o] = a4.y;
      As[cc + 2][o] = a4.z; As[cc + 3][o] = a4.w;
    }
    {
      int cc = tid >> 4, nn = (tid & 15) * 4;
      *(float4*)&Bs[cc][nn] = *(const float4*)(xb + (size_t)(c0 + cc) * 4096 + nB + nn);
    }
    __syncthreads();
#pragma unroll
    for (int kk = 0; kk < 16; kk++) {
      float a[4], bb[4];
      *(float4*)a  = *(const float4*)&As[kk][ty * 4];
      *(float4*)bb = *(const float4*)&Bs[kk][tx * 4];
#pragma unroll
      for (int i = 0; i < 4; i++)
#pragma unroll
        for (int j = 0; j < 4; j++) acc[i][j] += a[i] * bb[j];
    }
    __syncthreads();
  }
  const float QSCALE = 0.17677669529663687f * 1.4426950408889634f;  // scale*log2e
#pragma unroll
  for (int i = 0; i < 4; i++) {
    int o = oB + ty * 4 + i;
    int which = o >> 8, h = (o >> 5) & 7, d = o & 31;
    int bh = b * 8 + h;
    if (which == 2) {
      u32 lo = (u32)f2bf(acc[i][0]) | ((u32)f2bf(acc[i][1]) << 16);
      u32 hi = (u32)f2bf(acc[i][2]) | ((u32)f2bf(acc[i][3]) << 16);
      uint2 pk4; pk4.x = lo; pk4.y = hi;
      *(uint2*)(Vtg + ((size_t)bh * 32 + d) * 4096 + nB + tx * 4) = pk4;
    } else {
      float sc = (which == 0) ? QSCALE : 1.0f;
      u16* base = (which == 0) ? Qg : Kg;
      u16* dst = base + (size_t)bh * 4096 * 32 + d;
#pragma unroll
      for (int j = 0; j < 4; j++) {
        int n = nB + tx * 4 + j;
        dst[(size_t)n * 32] = f2bf(acc[i][j] * sc);
      }
    }
  }
}

// ---------------------------------------------------------------------------
// Kernel 2: conv3x3 + BN  -> localOut [b][c][n]  (unchanged)
// ---------------------------------------------------------------------------
__global__ __launch_bounds__(256) void conv3x3_bn_kernel(
    const float* __restrict__ x, const float* __restrict__ w,
    const float* __restrict__ g, const float* __restrict__ be,
    const float* __restrict__ mu, const float* __restrict__ var,
    float* __restrict__ out) {
  const int y  = blockIdx.x;
  const int oB = blockIdx.y * 64;
  const int b  = blockIdx.z;
  __shared__ float Xs[8][3][68];
  __shared__ float Ws[8][64][9];
  const int tid = threadIdx.x;
  const int tx = tid & 15, ty = tid >> 4;
  const float* xb = x + (size_t)b * 256 * 4096;
  float acc[4][4] = {};
  for (int c0 = 0; c0 < 256; c0 += 8) {
    for (int idx = tid; idx < 8 * 3 * 66; idx += 256) {
      int c = idx / 198;
      int rem = idx - c * 198;
      int r = rem / 66;
      int xx = rem - r * 66;
      int ys = y + r - 1, xs = xx - 1;
      float v = 0.f;
      if (ys >= 0 && ys < 64 && xs >= 0 && xs < 64)
        v = xb[(size_t)(c0 + c) * 4096 + ys * 64 + xs];
      Xs[c][r][xx] = v;
    }
    for (int idx = tid; idx < 64 * 8 * 9; idx += 256) {
      int o = idx / 72;
      int rem = idx - o * 72;
      int c = rem / 9;
      int t = rem - c * 9;
      Ws[c][o][t] = w[((size_t)(oB + o) * 256 + c0 + c) * 9 + t];
    }
    __syncthreads();
#pragma unroll
    for (int c = 0; c < 8; c++) {
      float xr[3][6];
#pragma unroll
      for (int r = 0; r < 3; r++)
#pragma unroll
        for (int j = 0; j < 6; j++) xr[r][j] = Xs[c][r][tx * 4 + j];
#pragma unroll
      for (int i = 0; i < 4; i++) {
        const float* wp = &Ws[c][ty * 4 + i][0];
        float wv[9];
#pragma unroll
        for (int t = 0; t < 9; t++) wv[t] = wp[t];
#pragma unroll
        for (int j = 0; j < 4; j++) {
          float s = acc[i][j];
          s += wv[0] * xr[0][j + 0] + wv[1] * xr[0][j + 1] + wv[2] * xr[0][j + 2];
          s += wv[3] * xr[1][j + 0] + wv[4] * xr[1][j + 1] + wv[5] * xr[1][j + 2];
          s += wv[6] * xr[2][j + 0] + wv[7] * xr[2][j + 1] + wv[8] * xr[2][j + 2];
          acc[i][j] = s;
        }
      }
    }
    __syncthreads();
  }
#pragma unroll
  for (int i = 0; i < 4; i++) {
    int o = oB + ty * 4 + i;
    float inv = g[o] * rsqrtf(var[o] + EPSV);
    float sh  = be[o] - mu[o] * inv;
    float4 r;
    r.x = acc[i][0] * inv + sh;
    r.y = acc[i][1] * inv + sh;
    r.z = acc[i][2] * inv + sh;
    r.w = acc[i][3] * inv + sh;
    *(float4*)(out + ((size_t)(b * 256 + o)) * 4096 + y * 64 + tx * 4) = r;
  }
}

// ---------------------------------------------------------------------------
// Kernel 3: MFMA flash attention.
// Qg/Kg: bf16 [bh][n][32] (Q pre-scaled), Vtg: bf16 [bh][d][4096]
// out: attnOut fp32 [b][c][n].
// Computes S^T = K.Q^T per 16x16 tile (C layout: row=m=4G+r, col=n=lane&15),
// online softmax over m via 2 shfl_xor, P^T -> B-frag via 16 lane shuffles,
// out^T[d][n] = V^T.P^T accumulated in C layout (matches output layout).
// grid: 1024 blocks (bh = bid>>6 so 64 consecutive blocks share K/V in L2),
// block: 256 = 4 waves, wave handles 16 q rows, block 64 q rows.
// ---------------------------------------------------------------------------
__global__ __launch_bounds__(256) void flash_mfma_kernel(
    const u16* __restrict__ Qg, const u16* __restrict__ Kg,
    const u16* __restrict__ Vtg, float* __restrict__ out) {
  __shared__ u16 Ks[64][40];   // [m][d], +8 pad: 2-way conflicts only
  __shared__ u16 Vt[32][72];   // [d][m], +8 pad
  const int bid = blockIdx.x;
  const int bh = bid >> 6;
  const int qt = bid & 63;
  const int tid = threadIdx.x;
  const int lane = tid & 63;
  const int wave = tid >> 6;
  const int n16 = lane & 15;
  const int G = lane >> 4;
  const int b = bh >> 3, h = bh & 7;

  // Q B-fragment: B[k=d=G*8+j][n=n16] = Q[qrow][G*8+j], one 16B load
  const int qrow = qt * 64 + wave * 16 + n16;
  const bf16x8 qf = *(const bf16x8*)(Qg + ((size_t)bh * 4096 + qrow) * 32 + G * 8);

  f32x4 O0 = {0.f, 0.f, 0.f, 0.f};
  f32x4 O1 = {0.f, 0.f, 0.f, 0.f};
  float mrow = -3.0e38f, lrow = 0.f;

  const u16* Kbh = Kg + (size_t)bh * 4096 * 32;
  const u16* Vbh = Vtg + (size_t)bh * 32 * 4096;

  const int krow = tid >> 2, kcol = (tid & 3) * 8;
  const int vd = tid >> 3, vm = (tid & 7) * 8;

  for (int m0 = 0; m0 < 4096; m0 += 64) {
    __syncthreads();
    *(uint4*)&Ks[krow][kcol] = *(const uint4*)(Kbh + (size_t)(m0 + krow) * 32 + kcol);
    *(uint4*)&Vt[vd][vm]     = *(const uint4*)(Vbh + (size_t)vd * 4096 + m0 + vm);
    __syncthreads();

    // S^T tiles: t covers m in [16t,16t+16); A = K rows, B = Q^T
    f32x4 S[4];
#pragma unroll
    for (int t = 0; t < 4; t++) {
      bf16x8 kf = *(const bf16x8*)&Ks[t * 16 + n16][G * 8];
      f32x4 z = {0.f, 0.f, 0.f, 0.f};
      S[t] = __builtin_amdgcn_mfma_f32_16x16x32_bf16(kf, qf, z, 0, 0, 0);
    }

    // row max over this tile's 64 m (16 local + lanes n16, n16+16, +32, +48)
    float mt = fmaxf(fmaxf(S[0].x, S[0].y), fmaxf(S[0].z, S[0].w));
#pragma unroll
    for (int t = 1; t < 4; t++)
      mt = fmaxf(mt, fmaxf(fmaxf(S[t].x, S[t].y), fmaxf(S[t].z, S[t].w)));
    mt = fmaxf(mt, __shfl_xor(mt, 16, 64));
    mt = fmaxf(mt, __shfl_xor(mt, 32, 64));
    float mnew = fmaxf(mrow, mt);
    float alpha = exp2f(mrow - mnew);
    mrow = mnew;

    // P = exp2(S - m), pack pairs (r,r+1) -> bf16x2 in u32
    float rsum = 0.f;
    u32 pk[4][2];
#pragma unroll
    for (int t = 0; t < 4; t++) {
      float p0 = exp2f(S[t].x - mnew);
      float p1 = exp2f(S[t].y - mnew);
      float p2 = exp2f(S[t].z - mnew);
      float p3 = exp2f(S[t].w - mnew);
      rsum += (p0 + p1) + (p2 + p3);
      u32 b0 = __float_as_uint(p0) + 0x8000u;
      u32 b1 = __float_as_uint(p1) + 0x8000u;
      u32 b2 = __float_as_uint(p2) + 0x8000u;
      u32 b3 = __float_as_uint(p3) + 0x8000u;
      pk[t][0] = __builtin_amdgcn_perm(b1, b0, 0x07060302u);
      pk[t][1] = __builtin_amdgcn_perm(b3, b2, 0x07060302u);
    }
    rsum += __shfl_xor(rsum, 16, 64);
    rsum += __shfl_xor(rsum, 32, 64);
    lrow = lrow * alpha + rsum;
    O0 *= alpha;
    O1 *= alpha;

    // P^T C-layout -> B-fragment: Bf[c][p] holds m = 32c+8G+2p(+1), n=n16.
    // source value pk[2c + (G>>1)][p&1] at lane 32*(G&1) + 16*(p>>1) + n16.
    u32 Bf[2][4];
#pragma unroll
    for (int p = 0; p < 4; p++) {
      int src = 32 * (G & 1) + 16 * (p >> 1) + n16;
      u32 v0 = __shfl(pk[0][p & 1], src, 64);
      u32 v1 = __shfl(pk[1][p & 1], src, 64);
      u32 v2 = __shfl(pk[2][p & 1], src, 64);
      u32 v3 = __shfl(pk[3][p & 1], src, 64);
      Bf[0][p] = (G >> 1) ? v1 : v0;
      Bf[1][p] = (G >> 1) ? v3 : v2;
    }

    // O^T += V^T . P^T  (A = V^T rows d, k chunks of 32 over m)
#pragma unroll
    for (int c = 0; c < 2; c++) {
      union { bf16x8 v; u32 u[4]; } bb;
      bb.u[0] = Bf[c][0]; bb.u[1] = Bf[c][1];
      bb.u[2] = Bf[c][2]; bb.u[3] = Bf[c][3];
      bf16x8 va0 = *(const bf16x8*)&Vt[n16][c * 32 + G * 8];
      bf16x8 va1 = *(const bf16x8*)&Vt[16 + n16][c * 32 + G * 8];
      O0 = __builtin_amdgcn_mfma_f32_16x16x32_bf16(va0, bb.v, O0, 0, 0, 0);
      O1 = __builtin_amdgcn_mfma_f32_16x16x32_bf16(va1, bb.v, O1, 0, 0, 0);
    }
  }

  const float rl = 1.0f / lrow;
  float* ob = out + (size_t)(b * 256 + h * 32) * 4096;
  const int nglob = qt * 64 + wave * 16 + n16;
#pragma unroll
  for (int r = 0; r < 4; r++) {
    ob[(size_t)(G * 4 + r) * 4096 + nglob]      = O0[r] * rl;
    ob[(size_t)(16 + G * 4 + r) * 4096 + nglob] = O1[r] * rl;
  }
}

// ---------------------------------------------------------------------------
// Kernel 4: Y = BN(w_proj(256x256) @ (attnOut + localOut)) -> d_out  (unchanged)
// ---------------------------------------------------------------------------
__global__ __launch_bounds__(256) void proj_gemm_bn_kernel(
    const float* __restrict__ S1, const float* __restrict__ S2,
    const float* __restrict__ w,
    const float* __restrict__ g, const float* __restrict__ be,
    const float* __restrict__ mu, const float* __restrict__ var,
    float* __restrict__ out) {
  __shared__ float As[16][68];
  __shared__ float Bs[16][64];
  const int nB = blockIdx.x * 64;
  const int oB = blockIdx.y * 64;
  const int b  = blockIdx.z;
  const int tid = threadIdx.x;
  const int tx = tid & 15, ty = tid >> 4;
  const float* s1b = S1 + (size_t)b * 256 * 4096;
  const float* s2b = S2 + (size_t)b * 256 * 4096;
  float acc[4][4] = {};
  for (int c0 = 0; c0 < 256; c0 += 16) {
    {
      int o = tid >> 2, cc = (tid & 3) * 4;
      float4 a4 = *(const float4*)(w + (size_t)(oB + o) * 256 + c0 + cc);
      As[cc + 0][o] = a4.x; As[cc + 1][o] = a4.y;
      As[cc + 2][o] = a4.z; As[cc + 3][o] = a4.w;
    }
    {
      int cc = tid >> 4, nn = (tid & 15) * 4;
      size_t off = (size_t)(c0 + cc) * 4096 + nB + nn;
      float4 b1 = *(const float4*)(s1b + off);
      float4 b2 = *(const float4*)(s2b + off);
      float4 bs;
      bs.x = b1.x + b2.x; bs.y = b1.y + b2.y;
      bs.z = b1.z + b2.z; bs.w = b1.w + b2.w;
      *(float4*)&Bs[cc][nn] = bs;
    }
    __syncthreads();
#pragma unroll
    for (int kk = 0; kk < 16; kk++) {
      float a[4], bb[4];
      *(float4*)a  = *(const float4*)&As[kk][ty * 4];
      *(float4*)bb = *(const float4*)&Bs[kk][tx * 4];
#pragma unroll
      for (int i = 0; i < 4; i++)
#pragma unroll
        for (int j = 0; j < 4; j++) acc[i][j] += a[i] * bb[j];
    }
    __syncthreads();
  }
#pragma unroll
  for (int i = 0; i < 4; i++) {
    int o = oB + ty * 4 + i;
    float inv = g[o] * rsqrtf(var[o] + EPSV);
    float sh  = be[o] - mu[o] * inv;
    float4 r;
    r.x = acc[i][0] * inv + sh;
    r.y = acc[i][1] * inv + sh;
    r.z = acc[i][2] * inv + sh;
    r.w = acc[i][3] * inv + sh;
    *(float4*)(out + ((size_t)(b * 256 + o)) * 4096 + nB + tx * 4) = r;
  }
}

extern "C" void kernel_launch(void* const* d_in, const int* in_sizes, int n_in,
                              void* d_out, int out_size, void* d_ws, size_t ws_size,
                              hipStream_t stream) {
  (void)in_sizes; (void)n_in; (void)out_size; (void)ws_size;
  const float* x       = (const float*)d_in[0];
  const float* w_qkv   = (const float*)d_in[1];
  const float* w_local = (const float*)d_in[2];
  const float* lg = (const float*)d_in[3];
  const float* lb = (const float*)d_in[4];
  const float* lm = (const float*)d_in[5];
  const float* lv = (const float*)d_in[6];
  const float* w_proj  = (const float*)d_in[7];
  const float* pg = (const float*)d_in[8];
  const float* pb = (const float*)d_in[9];
  const float* pm = (const float*)d_in[10];
  const float* pvr = (const float*)d_in[11];
  float* out = (float*)d_out;

  // ws layout: Q,K,Vt bf16 (2M u16 each = 12 MB), attnOut/localOut fp32 (8 MB each)
  u16* Q  = (u16*)d_ws;
  u16* K  = Q + 2097152;
  u16* Vt = K + 2097152;
  float* attnOut  = (float*)(Vt + 2097152);
  float* localOut = attnOut + 2097152;

  hipLaunchKernelGGL(conv3x3_bn_kernel, dim3(64, 4, 2), dim3(256), 0, stream,
                     x, w_local, lg, lb, lm, lv, localOut);
  hipLaunchKernelGGL(qkv_gemm_kernel, dim3(64, 12, 2), dim3(256), 0, stream,
                     x, w_qkv, Q, K, Vt);
  hipLaunchKernelGGL(flash_mfma_kernel, dim3(1024), dim3(256), 0, stream,
                     Q, K, Vt, attnOut);
  hipLaunchKernelGGL(proj_gemm_bn_kernel, dim3(64, 4, 2), dim3(256), 0, stream,
                     attnOut, localOut, w_proj, pg, pb, pm, pvr, out);
}

// Round 3
// 350.927 us; speedup vs baseline: 7.0695x; 2.2680x over previous
//
#include <hip/hip_runtime.h>

#define EPSV 1e-5f

typedef unsigned short u16;
typedef unsigned int u32;
typedef __attribute__((ext_vector_type(8))) short bf16x8;
typedef __attribute__((ext_vector_type(4))) float f32x4;

__device__ __forceinline__ u16 f2bf(float f) {
  u32 u = __float_as_uint(f);
  u32 r = (u + 0x7FFFu + ((u >> 16) & 1u)) >> 16;
  return (u16)r;
}
__device__ __forceinline__ u32 pack2bf(float a, float b) {
  return (u32)f2bf(a) | ((u32)f2bf(b) << 16);
}
__device__ __forceinline__ float bflo(u32 p) { return __uint_as_float(p << 16); }
__device__ __forceinline__ float bfhi(u32 p) { return __uint_as_float(p & 0xFFFF0000u); }

// ---------------------------------------------------------------------------
// Kernel 0: w_local fp32 [o][c][3][3] -> wb bf16 [tap][o][c]
// ---------------------------------------------------------------------------
__global__ __launch_bounds__(256) void wconv_kernel(
    const float* __restrict__ w, u16* __restrict__ wb) {
  const int o = blockIdx.x, c = threadIdx.x;
  const float* src = w + ((size_t)o * 256 + c) * 9;
  float t[9];
#pragma unroll
  for (int i = 0; i < 9; i++) t[i] = src[i];
#pragma unroll
  for (int tap = 0; tap < 9; tap++)
    wb[(size_t)tap * 65536 + o * 256 + c] = f2bf(t[tap]);
}

// ---------------------------------------------------------------------------
// Kernel 1: qkv = w_qkv(768x256) @ x[b](256x4096)
// outputs: Qg/Kg bf16 [bh][n][32] (Q pre-scaled), Vt bf16 [bh][d][4096],
// and (blocks with oB==0) xT bf16 [c>>4][b*4096+s][c&15] for the conv kernel.
// ---------------------------------------------------------------------------
__global__ __launch_bounds__(256) void qkv_gemm_kernel(
    const float* __restrict__ x, const float* __restrict__ w,
    u16* __restrict__ Qg, u16* __restrict__ Kg, u16* __restrict__ Vtg,
    u16* __restrict__ xT) {
  __shared__ float As[16][68];
  __shared__ float Bs[16][64];
  const int nB = blockIdx.x * 64;
  const int oB = blockIdx.y * 64;
  const int b  = blockIdx.z;
  const int tid = threadIdx.x;
  const int tx = tid & 15, ty = tid >> 4;
  const float* xb = x + (size_t)b * 256 * 4096;
  float acc[4][4] = {};
  for (int c0 = 0; c0 < 256; c0 += 16) {
    {
      int o = tid >> 2, cc = (tid & 3) * 4;
      float4 a4 = *(const float4*)(w + (size_t)(oB + o) * 256 + c0 + cc);
      As[cc + 0][o] = a4.x; As[cc + 1][o] = a4.y;
      As[cc + 2][o] = a4.z; As[cc + 3][o] = a4.w;
    }
    {
      int cc = tid >> 4, nn = (tid & 15) * 4;
      *(float4*)&Bs[cc][nn] = *(const float4*)(xb + (size_t)(c0 + cc) * 4096 + nB + nn);
    }
    __syncthreads();
#pragma unroll
    for (int kk = 0; kk < 16; kk++) {
      float a[4], bb[4];
      *(float4*)a  = *(const float4*)&As[kk][ty * 4];
      *(float4*)bb = *(const float4*)&Bs[kk][tx * 4];
#pragma unroll
      for (int i = 0; i < 4; i++)
#pragma unroll
        for (int j = 0; j < 4; j++) acc[i][j] += a[i] * bb[j];
    }
    // emit xT plane for the conv kernel (one oB block per (nB,b) tile)
    if (oB == 0) {
      int n = tid >> 2;            // 0..63
      int cq = (tid & 3) * 4;      // 0,4,8,12
      float v0 = Bs[cq + 0][n], v1 = Bs[cq + 1][n];
      float v2 = Bs[cq + 2][n], v3 = Bs[cq + 3][n];
      uint2 pk; pk.x = pack2bf(v0, v1); pk.y = pack2bf(v2, v3);
      *(uint2*)(xT + ((size_t)(c0 >> 4) * 8192 + b * 4096 + nB + n) * 16 + cq) = pk;
    }
    __syncthreads();
  }
  const float QSCALE = 0.17677669529663687f * 1.4426950408889634f;  // scale*log2e
#pragma unroll
  for (int i = 0; i < 4; i++) {
    int o = oB + ty * 4 + i;
    int which = o >> 8, h = (o >> 5) & 7, d = o & 31;
    int bh = b * 8 + h;
    if (which == 2) {
      uint2 pk4; pk4.x = pack2bf(acc[i][0], acc[i][1]); pk4.y = pack2bf(acc[i][2], acc[i][3]);
      *(uint2*)(Vtg + ((size_t)bh * 32 + d) * 4096 + nB + tx * 4) = pk4;
    } else {
      float sc = (which == 0) ? QSCALE : 1.0f;
      u16* base = (which == 0) ? Qg : Kg;
      u16* dst = base + (size_t)bh * 4096 * 32 + d;
#pragma unroll
      for (int j = 0; j < 4; j++) {
        int n = nB + tx * 4 + j;
        dst[(size_t)n * 32] = f2bf(acc[i][j] * sc);
      }
    }
  }
}

// ---------------------------------------------------------------------------
// Kernel 2: conv3x3 + BN via bf16 MFMA implicit GEMM -> localOut bf16 [b][c][n]
// grid (y=64, oB=4, b=2), block 256 = 4 waves; wave = 32o x 32n (2x2 16-tiles).
// B (x) staged in LDS channel-contiguous: tap shifts move the row index only.
// A (weights) read from global wb[tap][o][c] (L2-resident).
// ---------------------------------------------------------------------------
__global__ __launch_bounds__(256) void conv_mfma_kernel(
    const u16* __restrict__ xT, const u16* __restrict__ wb,
    const float* __restrict__ g, const float* __restrict__ be,
    const float* __restrict__ mu, const float* __restrict__ var,
    u16* __restrict__ out) {
  __shared__ u16 Xs[3 * 66 * 32];   // [r][xx][c32], row stride 64B
  const int y  = blockIdx.x;
  const int oB = blockIdx.y * 64;
  const int bb = blockIdx.z;
  const int tid = threadIdx.x;
  const int lane = tid & 63;
  const int wave = tid >> 6;
  const int n16 = lane & 15;
  const int G = lane >> 4;
  const int oW = oB + (wave >> 1) * 32;   // wave's o base
  const int nW = (wave & 1) * 32;         // wave's n base within the row

  f32x4 acc[2][2] = {};
  const u16* wbl = wb + (size_t)(oW + n16) * 256 + G * 8;

  for (int c0 = 0; c0 < 256; c0 += 32) {
    __syncthreads();
    for (int q = tid; q < 792; q += 256) {
      int r = q / 264;
      int rem = q - r * 264;
      int xx = rem >> 2, qu = rem & 3;
      int ys = y + r - 1, xs = xx - 1;
      uint4 val = {0u, 0u, 0u, 0u};
      if ((unsigned)ys < 64u && (unsigned)xs < 64u) {
        const u16* src = xT + ((size_t)((c0 >> 4) + (qu >> 1)) * 8192 +
                               bb * 4096 + ys * 64 + xs) * 16 + (qu & 1) * 8;
        val = *(const uint4*)src;
      }
      *(uint4*)&Xs[(r * 66 + xx) * 32 + qu * 8] = val;
    }
    __syncthreads();
#pragma unroll
    for (int tap = 0; tap < 9; tap++) {
      const int dy = tap / 3, dx = tap - dy * 3;
      bf16x8 a0 = *(const bf16x8*)(wbl + (size_t)tap * 65536 + c0);
      bf16x8 a1 = *(const bf16x8*)(wbl + (size_t)tap * 65536 + c0 + 16 * 256);
      bf16x8 b0 = *(const bf16x8*)&Xs[(dy * 66 + nW + dx + n16) * 32 + G * 8];
      bf16x8 b1 = *(const bf16x8*)&Xs[(dy * 66 + nW + 16 + dx + n16) * 32 + G * 8];
      acc[0][0] = __builtin_amdgcn_mfma_f32_16x16x32_bf16(a0, b0, acc[0][0], 0, 0, 0);
      acc[0][1] = __builtin_amdgcn_mfma_f32_16x16x32_bf16(a0, b1, acc[0][1], 0, 0, 0);
      acc[1][0] = __builtin_amdgcn_mfma_f32_16x16x32_bf16(a1, b0, acc[1][0], 0, 0, 0);
      acc[1][1] = __builtin_amdgcn_mfma_f32_16x16x32_bf16(a1, b1, acc[1][1], 0, 0, 0);
    }
  }

  u16* ob = out + (size_t)bb * 256 * 4096;
#pragma unroll
  for (int ot = 0; ot < 2; ot++) {
#pragma unroll
    for (int r = 0; r < 4; r++) {
      int o = oW + ot * 16 + G * 4 + r;
      float inv = g[o] * rsqrtf(var[o] + EPSV);
      float sh  = be[o] - mu[o] * inv;
#pragma unroll
      for (int nt = 0; nt < 2; nt++) {
        int nx = y * 64 + nW + nt * 16 + n16;
        ob[(size_t)o * 4096 + nx] = f2bf(acc[ot][nt][r] * inv + sh);
      }
    }
  }
}

// ---------------------------------------------------------------------------
// Kernel 3: MFMA flash attention (as R2), epilogue now stores bf16.
// ---------------------------------------------------------------------------
__global__ __launch_bounds__(256) void flash_mfma_kernel(
    const u16* __restrict__ Qg, const u16* __restrict__ Kg,
    const u16* __restrict__ Vtg, u16* __restrict__ out) {
  __shared__ u16 Ks[64][40];
  __shared__ u16 Vt[32][72];
  const int bid = blockIdx.x;
  const int bh = bid >> 6;
  const int qt = bid & 63;
  const int tid = threadIdx.x;
  const int lane = tid & 63;
  const int wave = tid >> 6;
  const int n16 = lane & 15;
  const int G = lane >> 4;
  const int b = bh >> 3, h = bh & 7;

  const int qrow = qt * 64 + wave * 16 + n16;
  const bf16x8 qf = *(const bf16x8*)(Qg + ((size_t)bh * 4096 + qrow) * 32 + G * 8);

  f32x4 O0 = {0.f, 0.f, 0.f, 0.f};
  f32x4 O1 = {0.f, 0.f, 0.f, 0.f};
  float mrow = -3.0e38f, lrow = 0.f;

  const u16* Kbh = Kg + (size_t)bh * 4096 * 32;
  const u16* Vbh = Vtg + (size_t)bh * 32 * 4096;

  const int krow = tid >> 2, kcol = (tid & 3) * 8;
  const int vd = tid >> 3, vm = (tid & 7) * 8;

  for (int m0 = 0; m0 < 4096; m0 += 64) {
    __syncthreads();
    *(uint4*)&Ks[krow][kcol] = *(const uint4*)(Kbh + (size_t)(m0 + krow) * 32 + kcol);
    *(uint4*)&Vt[vd][vm]     = *(const uint4*)(Vbh + (size_t)vd * 4096 + m0 + vm);
    __syncthreads();

    f32x4 S[4];
#pragma unroll
    for (int t = 0; t < 4; t++) {
      bf16x8 kf = *(const bf16x8*)&Ks[t * 16 + n16][G * 8];
      f32x4 z = {0.f, 0.f, 0.f, 0.f};
      S[t] = __builtin_amdgcn_mfma_f32_16x16x32_bf16(kf, qf, z, 0, 0, 0);
    }

    float mt = fmaxf(fmaxf(S[0].x, S[0].y), fmaxf(S[0].z, S[0].w));
#pragma unroll
    for (int t = 1; t < 4; t++)
      mt = fmaxf(mt, fmaxf(fmaxf(S[t].x, S[t].y), fmaxf(S[t].z, S[t].w)));
    mt = fmaxf(mt, __shfl_xor(mt, 16, 64));
    mt = fmaxf(mt, __shfl_xor(mt, 32, 64));
    float mnew = fmaxf(mrow, mt);
    float alpha = exp2f(mrow - mnew);
    mrow = mnew;

    float rsum = 0.f;
    u32 pk[4][2];
#pragma unroll
    for (int t = 0; t < 4; t++) {
      float p0 = exp2f(S[t].x - mnew);
      float p1 = exp2f(S[t].y - mnew);
      float p2 = exp2f(S[t].z - mnew);
      float p3 = exp2f(S[t].w - mnew);
      rsum += (p0 + p1) + (p2 + p3);
      u32 b0 = __float_as_uint(p0) + 0x8000u;
      u32 b1 = __float_as_uint(p1) + 0x8000u;
      u32 b2 = __float_as_uint(p2) + 0x8000u;
      u32 b3 = __float_as_uint(p3) + 0x8000u;
      pk[t][0] = __builtin_amdgcn_perm(b1, b0, 0x07060302u);
      pk[t][1] = __builtin_amdgcn_perm(b3, b2, 0x07060302u);
    }
    rsum += __shfl_xor(rsum, 16, 64);
    rsum += __shfl_xor(rsum, 32, 64);
    lrow = lrow * alpha + rsum;
    O0 *= alpha;
    O1 *= alpha;

    u32 Bf[2][4];
#pragma unroll
    for (int p = 0; p < 4; p++) {
      int src = 32 * (G & 1) + 16 * (p >> 1) + n16;
      u32 v0 = __shfl(pk[0][p & 1], src, 64);
      u32 v1 = __shfl(pk[1][p & 1], src, 64);
      u32 v2 = __shfl(pk[2][p & 1], src, 64);
      u32 v3 = __shfl(pk[3][p & 1], src, 64);
      Bf[0][p] = (G >> 1) ? v1 : v0;
      Bf[1][p] = (G >> 1) ? v3 : v2;
    }

#pragma unroll
    for (int c = 0; c < 2; c++) {
      union { bf16x8 v; u32 u[4]; } bbu;
      bbu.u[0] = Bf[c][0]; bbu.u[1] = Bf[c][1];
      bbu.u[2] = Bf[c][2]; bbu.u[3] = Bf[c][3];
      bf16x8 va0 = *(const bf16x8*)&Vt[n16][c * 32 + G * 8];
      bf16x8 va1 = *(const bf16x8*)&Vt[16 + n16][c * 32 + G * 8];
      O0 = __builtin_amdgcn_mfma_f32_16x16x32_bf16(va0, bbu.v, O0, 0, 0, 0);
      O1 = __builtin_amdgcn_mfma_f32_16x16x32_bf16(va1, bbu.v, O1, 0, 0, 0);
    }
  }

  const float rl = 1.0f / lrow;
  u16* ob = out + (size_t)(b * 256 + h * 32) * 4096;
  const int nglob = qt * 64 + wave * 16 + n16;
#pragma unroll
  for (int r = 0; r < 4; r++) {
    ob[(size_t)(G * 4 + r) * 4096 + nglob]      = f2bf(O0[r] * rl);
    ob[(size_t)(16 + G * 4 + r) * 4096 + nglob] = f2bf(O1[r] * rl);
  }
}

// ---------------------------------------------------------------------------
// Kernel 4: Y = BN(w_proj(256x256) @ (attnOut + localOut)), bf16 inputs.
// ---------------------------------------------------------------------------
__global__ __launch_bounds__(256) void proj_gemm_bn_kernel(
    const u16* __restrict__ S1, const u16* __restrict__ S2,
    const float* __restrict__ w,
    const float* __restrict__ g, const float* __restrict__ be,
    const float* __restrict__ mu, const float* __restrict__ var,
    float* __restrict__ out) {
  __shared__ float As[16][68];
  __shared__ float Bs[16][64];
  const int nB = blockIdx.x * 64;
  const int oB = blockIdx.y * 64;
  const int b  = blockIdx.z;
  const int tid = threadIdx.x;
  const int tx = tid & 15, ty = tid >> 4;
  const u16* s1b = S1 + (size_t)b * 256 * 4096;
  const u16* s2b = S2 + (size_t)b * 256 * 4096;
  float acc[4][4] = {};
  for (int c0 = 0; c0 < 256; c0 += 16) {
    {
      int o = tid >> 2, cc = (tid & 3) * 4;
      float4 a4 = *(const float4*)(w + (size_t)(oB + o) * 256 + c0 + cc);
      As[cc + 0][o] = a4.x; As[cc + 1][o] = a4.y;
      As[cc + 2][o] = a4.z; As[cc + 3][o] = a4.w;
    }
    {
      int cc = tid >> 4, nn = (tid & 15) * 4;
      size_t off = (size_t)(c0 + cc) * 4096 + nB + nn;
      uint2 p1 = *(const uint2*)(s1b + off);
      uint2 p2 = *(const uint2*)(s2b + off);
      float4 bs;
      bs.x = bflo(p1.x) + bflo(p2.x);
      bs.y = bfhi(p1.x) + bfhi(p2.x);
      bs.z = bflo(p1.y) + bflo(p2.y);
      bs.w = bfhi(p1.y) + bfhi(p2.y);
      *(float4*)&Bs[cc][nn] = bs;
    }
    __syncthreads();
#pragma unroll
    for (int kk = 0; kk < 16; kk++) {
      float a[4], bb[4];
      *(float4*)a  = *(const float4*)&As[kk][ty * 4];
      *(float4*)bb = *(const float4*)&Bs[kk][tx * 4];
#pragma unroll
      for (int i = 0; i < 4; i++)
#pragma unroll
        for (int j = 0; j < 4; j++) acc[i][j] += a[i] * bb[j];
    }
    __syncthreads();
  }
#pragma unroll
  for (int i = 0; i < 4; i++) {
    int o = oB + ty * 4 + i;
    float inv = g[o] * rsqrtf(var[o] + EPSV);
    float sh  = be[o] - mu[o] * inv;
    float4 r;
    r.x = acc[i][0] * inv + sh;
    r.y = acc[i][1] * inv + sh;
    r.z = acc[i][2] * inv + sh;
    r.w = acc[i][3] * inv + sh;
    *(float4*)(out + ((size_t)(b * 256 + o)) * 4096 + nB + tx * 4) = r;
  }
}

extern "C" void kernel_launch(void* const* d_in, const int* in_sizes, int n_in,
                              void* d_out, int out_size, void* d_ws, size_t ws_size,
                              hipStream_t stream) {
  (void)in_sizes; (void)n_in; (void)out_size; (void)ws_size;
  const float* x       = (const float*)d_in[0];
  const float* w_qkv   = (const float*)d_in[1];
  const float* w_local = (const float*)d_in[2];
  const float* lg = (const float*)d_in[3];
  const float* lb = (const float*)d_in[4];
  const float* lm = (const float*)d_in[5];
  const float* lv = (const float*)d_in[6];
  const float* w_proj  = (const float*)d_in[7];
  const float* pg = (const float*)d_in[8];
  const float* pb = (const float*)d_in[9];
  const float* pm = (const float*)d_in[10];
  const float* pvr = (const float*)d_in[11];
  float* out = (float*)d_out;

  // ws layout (u16 units): Q,K,Vt,xT 2M each; wb 589824; attnOut/localOut bf16 2M each
  u16* Q  = (u16*)d_ws;
  u16* K  = Q + 2097152;
  u16* Vt = K + 2097152;
  u16* xT = Vt + 2097152;
  u16* wb = xT + 2097152;
  u16* attnOut  = wb + 589824;
  u16* localOut = attnOut + 2097152;
  // total 13.2M u16 = 26.4 MB

  hipLaunchKernelGGL(wconv_kernel, dim3(256), dim3(256), 0, stream, w_local, wb);
  hipLaunchKernelGGL(qkv_gemm_kernel, dim3(64, 12, 2), dim3(256), 0, stream,
                     x, w_qkv, Q, K, Vt, xT);
  hipLaunchKernelGGL(conv_mfma_kernel, dim3(64, 4, 2), dim3(256), 0, stream,
                     xT, wb, lg, lb, lm, lv, localOut);
  hipLaunchKernelGGL(flash_mfma_kernel, dim3(1024), dim3(256), 0, stream,
                     Q, K, Vt, attnOut);
  hipLaunchKernelGGL(proj_gemm_bn_kernel, dim3(64, 4, 2), dim3(256), 0, stream,
                     attnOut, localOut, w_proj, pg, pb, pm, pvr, out);
}

// Round 4
// 296.458 us; speedup vs baseline: 8.3684x; 1.1837x over previous
//
#include <hip/hip_runtime.h>

#define EPSV 1e-5f

typedef unsigned short u16;
typedef unsigned int u32;
typedef __attribute__((ext_vector_type(8))) short bf16x8;
typedef __attribute__((ext_vector_type(4))) float f32x4;

__device__ __forceinline__ u16 f2bf(float f) {
  u32 u = __float_as_uint(f);
  u32 r = (u + 0x7FFFu + ((u >> 16) & 1u)) >> 16;
  return (u16)r;
}
__device__ __forceinline__ u32 pack2bf(float a, float b) {
  return (u32)f2bf(a) | ((u32)f2bf(b) << 16);
}
__device__ __forceinline__ float bflo(u32 p) { return __uint_as_float(p << 16); }
__device__ __forceinline__ float bfhi(u32 p) { return __uint_as_float(p & 0xFFFF0000u); }
__device__ __forceinline__ float fexp2(float x) {
  float r;
  asm("v_exp_f32 %0, %1" : "=v"(r) : "v"(x));
  return r;
}

// ---------------------------------------------------------------------------
// Kernel 0: w_local fp32 [o][c][3][3] -> wb bf16 [tap][o][c]
// ---------------------------------------------------------------------------
__global__ __launch_bounds__(256) void wconv_kernel(
    const float* __restrict__ w, u16* __restrict__ wb) {
  const int o = blockIdx.x, c = threadIdx.x;
  const float* src = w + ((size_t)o * 256 + c) * 9;
  float t[9];
#pragma unroll
  for (int i = 0; i < 9; i++) t[i] = src[i];
#pragma unroll
  for (int tap = 0; tap < 9; tap++)
    wb[(size_t)tap * 65536 + o * 256 + c] = f2bf(t[tap]);
}

// ---------------------------------------------------------------------------
// Kernel 1: qkv = w_qkv(768x256) @ x[b](256x4096)
// outputs: Qg/Kg bf16 [bh][n][32] (Q pre-scaled), Vt bf16 [bh][d][4096],
// and (blocks with oB==0) xT bf16 [c>>4][b*4096+s][c&15] for the conv kernel.
// ---------------------------------------------------------------------------
__global__ __launch_bounds__(256) void qkv_gemm_kernel(
    const float* __restrict__ x, const float* __restrict__ w,
    u16* __restrict__ Qg, u16* __restrict__ Kg, u16* __restrict__ Vtg,
    u16* __restrict__ xT) {
  __shared__ float As[16][68];
  __shared__ float Bs[16][64];
  const int nB = blockIdx.x * 64;
  const int oB = blockIdx.y * 64;
  const int b  = blockIdx.z;
  const int tid = threadIdx.x;
  const int tx = tid & 15, ty = tid >> 4;
  const float* xb = x + (size_t)b * 256 * 4096;
  float acc[4][4] = {};
  for (int c0 = 0; c0 < 256; c0 += 16) {
    {
      int o = tid >> 2, cc = (tid & 3) * 4;
      float4 a4 = *(const float4*)(w + (size_t)(oB + o) * 256 + c0 + cc);
      As[cc + 0][o] = a4.x; As[cc + 1][o] = a4.y;
      As[cc + 2][o] = a4.z; As[cc + 3][o] = a4.w;
    }
    {
      int cc = tid >> 4, nn = (tid & 15) * 4;
      *(float4*)&Bs[cc][nn] = *(const float4*)(xb + (size_t)(c0 + cc) * 4096 + nB + nn);
    }
    __syncthreads();
#pragma unroll
    for (int kk = 0; kk < 16; kk++) {
      float a[4], bb[4];
      *(float4*)a  = *(const float4*)&As[kk][ty * 4];
      *(float4*)bb = *(const float4*)&Bs[kk][tx * 4];
#pragma unroll
      for (int i = 0; i < 4; i++)
#pragma unroll
        for (int j = 0; j < 4; j++) acc[i][j] += a[i] * bb[j];
    }
    // emit xT plane for the conv kernel (one oB block per (nB,b) tile)
    if (oB == 0) {
      int n = tid >> 2;            // 0..63
      int cq = (tid & 3) * 4;      // 0,4,8,12
      float v0 = Bs[cq + 0][n], v1 = Bs[cq + 1][n];
      float v2 = Bs[cq + 2][n], v3 = Bs[cq + 3][n];
      uint2 pk; pk.x = pack2bf(v0, v1); pk.y = pack2bf(v2, v3);
      *(uint2*)(xT + ((size_t)(c0 >> 4) * 8192 + b * 4096 + nB + n) * 16 + cq) = pk;
    }
    __syncthreads();
  }
  const float QSCALE = 0.17677669529663687f * 1.4426950408889634f;  // scale*log2e
#pragma unroll
  for (int i = 0; i < 4; i++) {
    int o = oB + ty * 4 + i;
    int which = o >> 8, h = (o >> 5) & 7, d = o & 31;
    int bh = b * 8 + h;
    if (which == 2) {
      uint2 pk4; pk4.x = pack2bf(acc[i][0], acc[i][1]); pk4.y = pack2bf(acc[i][2], acc[i][3]);
      *(uint2*)(Vtg + ((size_t)bh * 32 + d) * 4096 + nB + tx * 4) = pk4;
    } else {
      float sc = (which == 0) ? QSCALE : 1.0f;
      u16* base = (which == 0) ? Qg : Kg;
      u16* dst = base + (size_t)bh * 4096 * 32 + d;
#pragma unroll
      for (int j = 0; j < 4; j++) {
        int n = nB + tx * 4 + j;
        dst[(size_t)n * 32] = f2bf(acc[i][j] * sc);
      }
    }
  }
}

// ---------------------------------------------------------------------------
// Kernel 2: conv3x3 + BN via bf16 MFMA implicit GEMM -> localOut bf16 [b][c][n]
// ---------------------------------------------------------------------------
__global__ __launch_bounds__(256) void conv_mfma_kernel(
    const u16* __restrict__ xT, const u16* __restrict__ wb,
    const float* __restrict__ g, const float* __restrict__ be,
    const float* __restrict__ mu, const float* __restrict__ var,
    u16* __restrict__ out) {
  __shared__ u16 Xs[3 * 66 * 32];   // [r][xx][c32], row stride 64B
  const int y  = blockIdx.x;
  const int oB = blockIdx.y * 64;
  const int bb = blockIdx.z;
  const int tid = threadIdx.x;
  const int lane = tid & 63;
  const int wave = tid >> 6;
  const int n16 = lane & 15;
  const int G = lane >> 4;
  const int oW = oB + (wave >> 1) * 32;   // wave's o base
  const int nW = (wave & 1) * 32;         // wave's n base within the row

  f32x4 acc[2][2] = {};
  const u16* wbl = wb + (size_t)(oW + n16) * 256 + G * 8;

  for (int c0 = 0; c0 < 256; c0 += 32) {
    __syncthreads();
    for (int q = tid; q < 792; q += 256) {
      int r = q / 264;
      int rem = q - r * 264;
      int xx = rem >> 2, qu = rem & 3;
      int ys = y + r - 1, xs = xx - 1;
      uint4 val = {0u, 0u, 0u, 0u};
      if ((unsigned)ys < 64u && (unsigned)xs < 64u) {
        const u16* src = xT + ((size_t)((c0 >> 4) + (qu >> 1)) * 8192 +
                               bb * 4096 + ys * 64 + xs) * 16 + (qu & 1) * 8;
        val = *(const uint4*)src;
      }
      *(uint4*)&Xs[(r * 66 + xx) * 32 + qu * 8] = val;
    }
    __syncthreads();
#pragma unroll
    for (int tap = 0; tap < 9; tap++) {
      const int dy = tap / 3, dx = tap - dy * 3;
      bf16x8 a0 = *(const bf16x8*)(wbl + (size_t)tap * 65536 + c0);
      bf16x8 a1 = *(const bf16x8*)(wbl + (size_t)tap * 65536 + c0 + 16 * 256);
      bf16x8 b0 = *(const bf16x8*)&Xs[(dy * 66 + nW + dx + n16) * 32 + G * 8];
      bf16x8 b1 = *(const bf16x8*)&Xs[(dy * 66 + nW + 16 + dx + n16) * 32 + G * 8];
      acc[0][0] = __builtin_amdgcn_mfma_f32_16x16x32_bf16(a0, b0, acc[0][0], 0, 0, 0);
      acc[0][1] = __builtin_amdgcn_mfma_f32_16x16x32_bf16(a0, b1, acc[0][1], 0, 0, 0);
      acc[1][0] = __builtin_amdgcn_mfma_f32_16x16x32_bf16(a1, b0, acc[1][0], 0, 0, 0);
      acc[1][1] = __builtin_amdgcn_mfma_f32_16x16x32_bf16(a1, b1, acc[1][1], 0, 0, 0);
    }
  }

  u16* ob = out + (size_t)bb * 256 * 4096;
#pragma unroll
  for (int ot = 0; ot < 2; ot++) {
#pragma unroll
    for (int r = 0; r < 4; r++) {
      int o = oW + ot * 16 + G * 4 + r;
      float inv = g[o] * rsqrtf(var[o] + EPSV);
      float sh  = be[o] - mu[o] * inv;
#pragma unroll
      for (int nt = 0; nt < 2; nt++) {
        int nx = y * 64 + nW + nt * 16 + n16;
        ob[(size_t)o * 4096 + nx] = f2bf(acc[ot][nt][r] * inv + sh);
      }
    }
  }
}

// ---------------------------------------------------------------------------
// Kernel 3: MFMA flash attention, barrier-free K-loop.
// Qg/Kg: bf16 [bh][n][32] (Q pre-scaled), Vtg: bf16 [bh][d][4096].
// No K/V LDS staging: kf/va fragments are coalesced 1KB wave reads from L2.
// Wave = 32 q-rows (2 B-frags) x 2048 m (m-split 2); block = 4 waves = 64 q.
// P^T (MFMA C-layout) -> B-frag via wave-private LDS (no bpermute, no barrier).
// Split-m partials merged once via LDS at the end.
// grid 1024 (bh = bid>>6), block 256.
// ---------------------------------------------------------------------------
__global__ __launch_bounds__(256, 4) void flash_mfma_kernel(
    const u16* __restrict__ Qg, const u16* __restrict__ Kg,
    const u16* __restrict__ Vtg, u16* __restrict__ out) {
  __shared__ u32 Ps[4][32 * 36];      // per-wave P-transpose scratch (pad 36)
  __shared__ float MX[2][64][20];     // merge exchange
  const int bid = blockIdx.x;
  const int bh = bid >> 6, qt = bid & 63;
  const int tid = threadIdx.x, lane = tid & 63, w = tid >> 6;
  const int n16 = lane & 15, G = lane >> 4;
  const int g = w >> 1, mh = w & 1;
  const int b = bh >> 3, h = bh & 7;
  const int qbase = qt * 64 + g * 32;

  const u16* Qp = Qg + ((size_t)bh * 4096 + qbase) * 32;
  const bf16x8 qf0 = *(const bf16x8*)(Qp + (size_t)n16 * 32 + G * 8);
  const bf16x8 qf1 = *(const bf16x8*)(Qp + (size_t)(16 + n16) * 32 + G * 8);

  f32x4 O00 = {0.f,0.f,0.f,0.f}, O01 = {0.f,0.f,0.f,0.f};
  f32x4 O10 = {0.f,0.f,0.f,0.f}, O11 = {0.f,0.f,0.f,0.f};
  float m0 = -3.0e38f, m1 = -3.0e38f, l0 = 0.f, l1 = 0.f;

  const u16* Kb = Kg + ((size_t)bh * 4096 + mh * 2048) * 32;
  const u16* Vb = Vtg + (size_t)bh * 32 * 4096 + mh * 2048;
  u32* Pw = Ps[w];

  for (int it = 0; it < 32; ++it) {
    const u16* Kt = Kb + (size_t)it * 64 * 32;
    bf16x8 kf0 = *(const bf16x8*)(Kt + (size_t)(n16) * 32 + G * 8);
    bf16x8 kf1 = *(const bf16x8*)(Kt + (size_t)(16 + n16) * 32 + G * 8);
    bf16x8 kf2 = *(const bf16x8*)(Kt + (size_t)(32 + n16) * 32 + G * 8);
    bf16x8 kf3 = *(const bf16x8*)(Kt + (size_t)(48 + n16) * 32 + G * 8);
    const f32x4 z = {0.f, 0.f, 0.f, 0.f};
    f32x4 S0[4], S1[4];
    S0[0] = __builtin_amdgcn_mfma_f32_16x16x32_bf16(kf0, qf0, z, 0, 0, 0);
    S0[1] = __builtin_amdgcn_mfma_f32_16x16x32_bf16(kf1, qf0, z, 0, 0, 0);
    S0[2] = __builtin_amdgcn_mfma_f32_16x16x32_bf16(kf2, qf0, z, 0, 0, 0);
    S0[3] = __builtin_amdgcn_mfma_f32_16x16x32_bf16(kf3, qf0, z, 0, 0, 0);
    S1[0] = __builtin_amdgcn_mfma_f32_16x16x32_bf16(kf0, qf1, z, 0, 0, 0);
    S1[1] = __builtin_amdgcn_mfma_f32_16x16x32_bf16(kf1, qf1, z, 0, 0, 0);
    S1[2] = __builtin_amdgcn_mfma_f32_16x16x32_bf16(kf2, qf1, z, 0, 0, 0);
    S1[3] = __builtin_amdgcn_mfma_f32_16x16x32_bf16(kf3, qf1, z, 0, 0, 0);

    float mt0 = fmaxf(fmaxf(S0[0].x, S0[0].y), fmaxf(S0[0].z, S0[0].w));
    float mt1 = fmaxf(fmaxf(S1[0].x, S1[0].y), fmaxf(S1[0].z, S1[0].w));
#pragma unroll
    for (int t = 1; t < 4; t++) {
      mt0 = fmaxf(mt0, fmaxf(fmaxf(S0[t].x, S0[t].y), fmaxf(S0[t].z, S0[t].w)));
      mt1 = fmaxf(mt1, fmaxf(fmaxf(S1[t].x, S1[t].y), fmaxf(S1[t].z, S1[t].w)));
    }
    mt0 = fmaxf(mt0, __shfl_xor(mt0, 16, 64));
    mt0 = fmaxf(mt0, __shfl_xor(mt0, 32, 64));
    mt1 = fmaxf(mt1, __shfl_xor(mt1, 16, 64));
    mt1 = fmaxf(mt1, __shfl_xor(mt1, 32, 64));
    float mn0 = fmaxf(m0, mt0), mn1 = fmaxf(m1, mt1);
    if (__any((mt0 > m0) | (mt1 > m1))) {
      float a0 = fexp2(m0 - mn0);
      float a1 = fexp2(m1 - mn1);
      l0 *= a0; l1 *= a1;
      O00 *= a0; O01 *= a0; O10 *= a1; O11 *= a1;
    }
    m0 = mn0; m1 = mn1;

    // P = exp2(S - m): pack (truncating) and write to wave-private LDS.
    float rs0 = 0.f, rs1 = 0.f;
#pragma unroll
    for (int t = 0; t < 4; t++) {
      float p0 = fexp2(S0[t].x - m0);
      float p1 = fexp2(S0[t].y - m0);
      float p2 = fexp2(S0[t].z - m0);
      float p3 = fexp2(S0[t].w - m0);
      rs0 += (p0 + p1) + (p2 + p3);
      uint2 pr;
      pr.x = __builtin_amdgcn_perm(__float_as_uint(p1), __float_as_uint(p0), 0x07060302u);
      pr.y = __builtin_amdgcn_perm(__float_as_uint(p3), __float_as_uint(p2), 0x07060302u);
      *(uint2*)&Pw[n16 * 36 + 8 * t + 2 * G] = pr;
      float q0 = fexp2(S1[t].x - m1);
      float q1 = fexp2(S1[t].y - m1);
      float q2 = fexp2(S1[t].z - m1);
      float q3 = fexp2(S1[t].w - m1);
      rs1 += (q0 + q1) + (q2 + q3);
      uint2 qr;
      qr.x = __builtin_amdgcn_perm(__float_as_uint(q1), __float_as_uint(q0), 0x07060302u);
      qr.y = __builtin_amdgcn_perm(__float_as_uint(q3), __float_as_uint(q2), 0x07060302u);
      *(uint2*)&Pw[(16 + n16) * 36 + 8 * t + 2 * G] = qr;
    }
    rs0 += __shfl_xor(rs0, 16, 64);
    rs0 += __shfl_xor(rs0, 32, 64);
    rs1 += __shfl_xor(rs1, 16, 64);
    rs1 += __shfl_xor(rs1, 32, 64);
    l0 += rs0; l1 += rs1;

    // O^T += V^T . P^T ; va from global (L2), Bf from wave-private LDS.
#pragma unroll
    for (int c = 0; c < 2; c++) {
      const u16* Vp = Vb + (size_t)it * 64 + c * 32 + G * 8;
      bf16x8 va0 = *(const bf16x8*)(Vp + (size_t)n16 * 4096);
      bf16x8 va1 = *(const bf16x8*)(Vp + (size_t)(16 + n16) * 4096);
      union { uint4 u; bf16x8 v; } B0, B1;
      B0.u = *(uint4*)&Pw[n16 * 36 + 16 * c + 4 * G];
      B1.u = *(uint4*)&Pw[(16 + n16) * 36 + 16 * c + 4 * G];
      O00 = __builtin_amdgcn_mfma_f32_16x16x32_bf16(va0, B0.v, O00, 0, 0, 0);
      O01 = __builtin_amdgcn_mfma_f32_16x16x32_bf16(va1, B0.v, O01, 0, 0, 0);
      O10 = __builtin_amdgcn_mfma_f32_16x16x32_bf16(va0, B1.v, O10, 0, 0, 0);
      O11 = __builtin_amdgcn_mfma_f32_16x16x32_bf16(va1, B1.v, O11, 0, 0, 0);
    }
  }

  // merge m-split pairs (waves 2g / 2g+1) and store
  if (mh == 1) {
    float* dst = &MX[g][lane][0];
    *(f32x4*)(dst + 0)  = O00;
    *(f32x4*)(dst + 4)  = O01;
    *(f32x4*)(dst + 8)  = O10;
    *(f32x4*)(dst + 12) = O11;
    dst[16] = m0; dst[17] = l0; dst[18] = m1; dst[19] = l1;
  }
  __syncthreads();
  if (mh == 0) {
    const float* src = &MX[g][lane][0];
    f32x4 P00 = *(const f32x4*)(src + 0);
    f32x4 P01 = *(const f32x4*)(src + 4);
    f32x4 P10 = *(const f32x4*)(src + 8);
    f32x4 P11 = *(const f32x4*)(src + 12);
    float pm0 = src[16], pl0 = src[17], pm1 = src[18], pl1 = src[19];
    u16* ob = out + (size_t)(b * 256 + h * 32) * 4096;

    float M0 = fmaxf(m0, pm0);
    float se0 = fexp2(m0 - M0), so0 = fexp2(pm0 - M0);
    float rl0 = 1.0f / (l0 * se0 + pl0 * so0);
    float M1 = fmaxf(m1, pm1);
    float se1 = fexp2(m1 - M1), so1 = fexp2(pm1 - M1);
    float rl1 = 1.0f / (l1 * se1 + pl1 * so1);
    const int col0 = qbase + n16, col1 = qbase + 16 + n16;
#pragma unroll
    for (int r = 0; r < 4; r++) {
      ob[(size_t)(G * 4 + r) * 4096 + col0]      = f2bf((O00[r] * se0 + P00[r] * so0) * rl0);
      ob[(size_t)(16 + G * 4 + r) * 4096 + col0] = f2bf((O01[r] * se0 + P01[r] * so0) * rl0);
      ob[(size_t)(G * 4 + r) * 4096 + col1]      = f2bf((O10[r] * se1 + P10[r] * so1) * rl1);
      ob[(size_t)(16 + G * 4 + r) * 4096 + col1] = f2bf((O11[r] * se1 + P11[r] * so1) * rl1);
    }
  }
}

// ---------------------------------------------------------------------------
// Kernel 4: Y = BN(w_proj(256x256) @ (attnOut + localOut)), bf16 inputs.
// ---------------------------------------------------------------------------
__global__ __launch_bounds__(256) void proj_gemm_bn_kernel(
    const u16* __restrict__ S1, const u16* __restrict__ S2,
    const float* __restrict__ w,
    const float* __restrict__ g, const float* __restrict__ be,
    const float* __restrict__ mu, const float* __restrict__ var,
    float* __restrict__ out) {
  __shared__ float As[16][68];
  __shared__ float Bs[16][64];
  const int nB = blockIdx.x * 64;
  const int oB = blockIdx.y * 64;
  const int b  = blockIdx.z;
  const int tid = threadIdx.x;
  const int tx = tid & 15, ty = tid >> 4;
  const u16* s1b = S1 + (size_t)b * 256 * 4096;
  const u16* s2b = S2 + (size_t)b * 256 * 4096;
  float acc[4][4] = {};
  for (int c0 = 0; c0 < 256; c0 += 16) {
    {
      int o = tid >> 2, cc = (tid & 3) * 4;
      float4 a4 = *(const float4*)(w + (size_t)(oB + o) * 256 + c0 + cc);
      As[cc + 0][o] = a4.x; As[cc + 1][o] = a4.y;
      As[cc + 2][o] = a4.z; As[cc + 3][o] = a4.w;
    }
    {
      int cc = tid >> 4, nn = (tid & 15) * 4;
      size_t off = (size_t)(c0 + cc) * 4096 + nB + nn;
      uint2 p1 = *(const uint2*)(s1b + off);
      uint2 p2 = *(const uint2*)(s2b + off);
      float4 bs;
      bs.x = bflo(p1.x) + bflo(p2.x);
      bs.y = bfhi(p1.x) + bfhi(p2.x);
      bs.z = bflo(p1.y) + bflo(p2.y);
      bs.w = bfhi(p1.y) + bfhi(p2.y);
      *(float4*)&Bs[cc][nn] = bs;
    }
    __syncthreads();
#pragma unroll
    for (int kk = 0; kk < 16; kk++) {
      float a[4], bb[4];
      *(float4*)a  = *(const float4*)&As[kk][ty * 4];
      *(float4*)bb = *(const float4*)&Bs[kk][tx * 4];
#pragma unroll
      for (int i = 0; i < 4; i++)
#pragma unroll
        for (int j = 0; j < 4; j++) acc[i][j] += a[i] * bb[j];
    }
    __syncthreads();
  }
#pragma unroll
  for (int i = 0; i < 4; i++) {
    int o = oB + ty * 4 + i;
    float inv = g[o] * rsqrtf(var[o] + EPSV);
    float sh  = be[o] - mu[o] * inv;
    float4 r;
    r.x = acc[i][0] * inv + sh;
    r.y = acc[i][1] * inv + sh;
    r.z = acc[i][2] * inv + sh;
    r.w = acc[i][3] * inv + sh;
    *(float4*)(out + ((size_t)(b * 256 + o)) * 4096 + nB + tx * 4) = r;
  }
}

extern "C" void kernel_launch(void* const* d_in, const int* in_sizes, int n_in,
                              void* d_out, int out_size, void* d_ws, size_t ws_size,
                              hipStream_t stream) {
  (void)in_sizes; (void)n_in; (void)out_size; (void)ws_size;
  const float* x       = (const float*)d_in[0];
  const float* w_qkv   = (const float*)d_in[1];
  const float* w_local = (const float*)d_in[2];
  const float* lg = (const float*)d_in[3];
  const float* lb = (const float*)d_in[4];
  const float* lm = (const float*)d_in[5];
  const float* lv = (const float*)d_in[6];
  const float* w_proj  = (const float*)d_in[7];
  const float* pg = (const float*)d_in[8];
  const float* pb = (const float*)d_in[9];
  const float* pm = (const float*)d_in[10];
  const float* pvr = (const float*)d_in[11];
  float* out = (float*)d_out;

  // ws layout (u16 units): Q,K,Vt,xT 2M each; wb 589824; attnOut/localOut bf16 2M each
  u16* Q  = (u16*)d_ws;
  u16* K  = Q + 2097152;
  u16* Vt = K + 2097152;
  u16* xT = Vt + 2097152;
  u16* wb = xT + 2097152;
  u16* attnOut  = wb + 589824;
  u16* localOut = attnOut + 2097152;

  hipLaunchKernelGGL(wconv_kernel, dim3(256), dim3(256), 0, stream, w_local, wb);
  hipLaunchKernelGGL(qkv_gemm_kernel, dim3(64, 12, 2), dim3(256), 0, stream,
                     x, w_qkv, Q, K, Vt, xT);
  hipLaunchKernelGGL(conv_mfma_kernel, dim3(64, 4, 2), dim3(256), 0, stream,
                     xT, wb, lg, lb, lm, lv, localOut);
  hipLaunchKernelGGL(flash_mfma_kernel, dim3(1024), dim3(256), 0, stream,
                     Q, K, Vt, attnOut);
  hipLaunchKernelGGL(proj_gemm_bn_kernel, dim3(64, 4, 2), dim3(256), 0, stream,
                     attnOut, localOut, w_proj, pg, pb, pm, pvr, out);
}

// Round 5
// 239.185 us; speedup vs baseline: 10.3722x; 1.2394x over previous
//
#include <hip/hip_runtime.h>

#define EPSV 1e-5f

typedef unsigned short u16;
typedef unsigned int u32;
typedef __attribute__((ext_vector_type(8))) short bf16x8;
typedef __attribute__((ext_vector_type(4))) float f32x4;

__device__ __forceinline__ u16 f2bf(float f) {
  u32 u = __float_as_uint(f);
  u32 r = (u + 0x7FFFu + ((u >> 16) & 1u)) >> 16;
  return (u16)r;
}
__device__ __forceinline__ float fexp2(float x) {
  float r;
  asm("v_exp_f32 %0, %1" : "=v"(r) : "v"(x));
  return r;
}

#define MFMA(a, b, c) __builtin_amdgcn_mfma_f32_16x16x32_bf16((a), (b), (c), 0, 0, 0)

// ---------------------------------------------------------------------------
// prep_x: x fp32 [b][c][4096] -> xT bf16 [(c>>4)][s=b*4096+n][c&15]
// LDS transpose so reads AND writes are coalesced.
// grid (16 n-tiles, 16 c-blocks, 2 b), block 256
// ---------------------------------------------------------------------------
__global__ __launch_bounds__(256) void prep_x_kernel(
    const float* __restrict__ x, u16* __restrict__ xT) {
  __shared__ float Ls[16][260];
  const int nt = blockIdx.x, cb = blockIdx.y, b = blockIdx.z;
  const int tid = threadIdx.x;
  const int cc0 = tid >> 6, n4 = (tid & 63) * 4;
  const float* xb = x + ((size_t)(b * 256 + cb * 16)) * 4096 + nt * 256;
#pragma unroll
  for (int j = 0; j < 4; j++) {
    int cc = j * 4 + cc0;
    *(float4*)&Ls[cc][n4] = *(const float4*)(xb + (size_t)cc * 4096 + n4);
  }
  __syncthreads();
  const int n = tid;
  u16 buf[16];
#pragma unroll
  for (int c = 0; c < 16; c++) buf[c] = f2bf(Ls[c][n]);
  u16* dst = xT + ((size_t)cb * 8192 + b * 4096 + nt * 256 + n) * 16;
  *(uint4*)(dst) = *(uint4*)&buf[0];
  *(uint4*)(dst + 8) = *(uint4*)&buf[8];
}

// ---------------------------------------------------------------------------
// prep_w: cast all weights to bf16. QSCALE*log2e folded into Wq rows (o<256).
// wqkvb [o][c] (768x256); wprojb [o][c] (256x256); wb [tap][o][c] (9x256x256)
// ---------------------------------------------------------------------------
__global__ __launch_bounds__(256) void prep_w_kernel(
    const float* __restrict__ wqkv, const float* __restrict__ wproj,
    const float* __restrict__ wloc,
    u16* __restrict__ wqkvb, u16* __restrict__ wprojb, u16* __restrict__ wb) {
  const int bid = blockIdx.x, c = threadIdx.x;
  const float QSCALE = 0.17677669529663687f * 1.4426950408889634f;
  if (bid < 768) {
    float sc = (bid < 256) ? QSCALE : 1.0f;
    wqkvb[bid * 256 + c] = f2bf(wqkv[bid * 256 + c] * sc);
  } else if (bid < 1024) {
    int o = bid - 768;
    wprojb[o * 256 + c] = f2bf(wproj[o * 256 + c]);
  } else {
    int o = bid - 1024;
    const float* src = wloc + ((size_t)o * 256 + c) * 9;
#pragma unroll
    for (int tap = 0; tap < 9; tap++)
      wb[tap * 65536 + o * 256 + c] = f2bf(src[tap]);
  }
}

// ---------------------------------------------------------------------------
// qkv MFMA GEMM: [768 o] x [256 c] x [8192 s], A=wqkvb, B=xT, no LDS.
// grid (64 nB=128-tiles, 12 oB=64-tiles); wave = 32o x 64n.
// Q/K bf16 [bh][n][32] (Q pre-scaled via weights), Vt bf16 [bh][d][4096].
// ---------------------------------------------------------------------------
__global__ __launch_bounds__(256, 4) void qkv_mfma_kernel(
    const u16* __restrict__ xT, const u16* __restrict__ wqkvb,
    u16* __restrict__ Qg, u16* __restrict__ Kg, u16* __restrict__ Vtg) {
  const int nB = blockIdx.x * 128;
  const int oB = blockIdx.y * 64;
  const int tid = threadIdx.x, lane = tid & 63, wv = tid >> 6;
  const int n16 = lane & 15, G = lane >> 4;
  const int waveO = oB + (wv >> 1) * 32;
  const int waveN = nB + (wv & 1) * 64;
  f32x4 acc[2][4] = {};
  const u16* Ap = wqkvb + (size_t)(waveO + n16) * 256 + G * 8;
  const u16* Bp = xT + ((size_t)(G >> 1) * 8192 + waveN + n16) * 16 + (G & 1) * 8;
  for (int c0 = 0; c0 < 256; c0 += 32) {
    bf16x8 a0 = *(const bf16x8*)(Ap + c0);
    bf16x8 a1 = *(const bf16x8*)(Ap + 16 * 256 + c0);
    const u16* bp = Bp + (size_t)(c0 >> 4) * 131072;
    bf16x8 b0 = *(const bf16x8*)(bp);
    bf16x8 b1 = *(const bf16x8*)(bp + 256);
    bf16x8 b2 = *(const bf16x8*)(bp + 512);
    bf16x8 b3 = *(const bf16x8*)(bp + 768);
    acc[0][0] = MFMA(a0, b0, acc[0][0]);
    acc[0][1] = MFMA(a0, b1, acc[0][1]);
    acc[0][2] = MFMA(a0, b2, acc[0][2]);
    acc[0][3] = MFMA(a0, b3, acc[0][3]);
    acc[1][0] = MFMA(a1, b0, acc[1][0]);
    acc[1][1] = MFMA(a1, b1, acc[1][1]);
    acc[1][2] = MFMA(a1, b2, acc[1][2]);
    acc[1][3] = MFMA(a1, b3, acc[1][3]);
  }
  const int which = oB >> 8;
  if (which < 2) {
    u16* base = which ? Kg : Qg;
#pragma unroll
    for (int i = 0; i < 2; i++) {
      int o0 = waveO + i * 16 + G * 4;
      int h = (o0 >> 5) & 7, d0 = o0 & 31;
#pragma unroll
      for (int j = 0; j < 4; j++) {
        int s = waveN + j * 16 + n16;
        int b = s >> 12, n = s & 4095;
        u16 pk[4];
#pragma unroll
        for (int r = 0; r < 4; r++) pk[r] = f2bf(acc[i][j][r]);
        *(uint2*)(base + ((size_t)(b * 8 + h) * 4096 + n) * 32 + d0) = *(uint2*)pk;
      }
    }
  } else {
#pragma unroll
    for (int i = 0; i < 2; i++) {
      int o0 = waveO + i * 16 + G * 4;
      int h = (o0 >> 5) & 7, d0 = o0 & 31;
#pragma unroll
      for (int j = 0; j < 4; j++) {
        int s = waveN + j * 16 + n16;
        int b = s >> 12, n = s & 4095;
        u16* vp = Vtg + ((size_t)(b * 8 + h) * 32 + d0) * 4096 + n;
#pragma unroll
        for (int r = 0; r < 4; r++) vp[(size_t)r * 4096] = f2bf(acc[i][j][r]);
      }
    }
  }
}

// ---------------------------------------------------------------------------
// conv3x3+BN MFMA, direct-from-L2 (no LDS, no barriers). Halo via signed
// spatial offset; x-edge lanes cndmask'ed to zero; y-edge taps skipped.
// grid (128 nB=64-tiles == one row y, 4 oB=64-tiles); wave = 32o x 32n.
// out: localT bf16 [(c>>4)][s][c&15]
// ---------------------------------------------------------------------------
__global__ __launch_bounds__(256, 4) void conv_mfma_kernel(
    const u16* __restrict__ xT, const u16* __restrict__ wb,
    const float* __restrict__ g, const float* __restrict__ be,
    const float* __restrict__ mu, const float* __restrict__ var,
    u16* __restrict__ localT) {
  const int nB = blockIdx.x * 64;
  const int oB = blockIdx.y * 64;
  const int tid = threadIdx.x, lane = tid & 63, wv = tid >> 6;
  const int n16 = lane & 15, G = lane >> 4;
  const int waveO = oB + (wv >> 1) * 32;
  const int waveN = nB + (wv & 1) * 32;
  const int y = (nB >> 6) & 63;
  const int x0 = waveN & 63;            // 0 or 32
  f32x4 acc[2][2] = {};
  const u16* Ap = wb + (size_t)(waveO + n16) * 256 + G * 8;
  const u16* Bp = xT + ((size_t)(G >> 1) * 8192 + waveN + n16) * 16 + (G & 1) * 8;
  const bf16x8 z = {0, 0, 0, 0, 0, 0, 0, 0};
  for (int c0 = 0; c0 < 256; c0 += 32) {
    const u16* bp = Bp + (size_t)(c0 >> 4) * 131072;
    const u16* ap = Ap + c0;
#pragma unroll
    for (int tap = 0; tap < 9; tap++) {
      const int dy = tap / 3 - 1, dx = tap % 3 - 1;
      int yy = y + dy;
      if ((unsigned)yy >= 64u) continue;
      bf16x8 a0 = *(const bf16x8*)(ap + (size_t)tap * 65536);
      bf16x8 a1 = *(const bf16x8*)(ap + (size_t)tap * 65536 + 16 * 256);
      const int off = dy * 64 + dx;
      bf16x8 b0, b1;
      if (dx == 0) {
        b0 = *(const bf16x8*)(bp + (ptrdiff_t)off * 16);
        b1 = *(const bf16x8*)(bp + (ptrdiff_t)(off + 16) * 16);
      } else {
        bool v0 = (unsigned)(x0 + n16 + dx) < 64u;
        bool v1 = (unsigned)(x0 + 16 + n16 + dx) < 64u;
        int o0 = v0 ? off : 0;
        int o1 = v1 ? (off + 16) : 16;
        bf16x8 t0 = *(const bf16x8*)(bp + (ptrdiff_t)o0 * 16);
        bf16x8 t1 = *(const bf16x8*)(bp + (ptrdiff_t)o1 * 16);
        b0 = v0 ? t0 : z;
        b1 = v1 ? t1 : z;
      }
      acc[0][0] = MFMA(a0, b0, acc[0][0]);
      acc[0][1] = MFMA(a0, b1, acc[0][1]);
      acc[1][0] = MFMA(a1, b0, acc[1][0]);
      acc[1][1] = MFMA(a1, b1, acc[1][1]);
    }
  }
#pragma unroll
  for (int i = 0; i < 2; i++) {
    int o0 = waveO + i * 16 + G * 4;
    float inv[4], sh[4];
#pragma unroll
    for (int r = 0; r < 4; r++) {
      int o = o0 + r;
      float iv = g[o] * rsqrtf(var[o] + EPSV);
      inv[r] = iv; sh[r] = be[o] - mu[o] * iv;
    }
#pragma unroll
    for (int j = 0; j < 2; j++) {
      int s = waveN + j * 16 + n16;
      u16 pk[4];
#pragma unroll
      for (int r = 0; r < 4; r++) pk[r] = f2bf(acc[i][j][r] * inv[r] + sh[r]);
      *(uint2*)(localT + ((size_t)(o0 >> 4) * 8192 + s) * 16 + (o0 & 15)) = *(uint2*)pk;
    }
  }
}

// ---------------------------------------------------------------------------
// flash attention (R4 structure), epilogue now emits attnT xT-style layout.
// ---------------------------------------------------------------------------
__global__ __launch_bounds__(256, 4) void flash_mfma_kernel(
    const u16* __restrict__ Qg, const u16* __restrict__ Kg,
    const u16* __restrict__ Vtg, u16* __restrict__ attnT) {
  __shared__ u32 Ps[4][32 * 36];
  __shared__ float MX[2][64][20];
  const int bid = blockIdx.x;
  const int bh = bid >> 6, qt = bid & 63;
  const int tid = threadIdx.x, lane = tid & 63, w = tid >> 6;
  const int n16 = lane & 15, G = lane >> 4;
  const int g = w >> 1, mh = w & 1;
  const int b = bh >> 3, h = bh & 7;
  const int qbase = qt * 64 + g * 32;

  const u16* Qp = Qg + ((size_t)bh * 4096 + qbase) * 32;
  const bf16x8 qf0 = *(const bf16x8*)(Qp + (size_t)n16 * 32 + G * 8);
  const bf16x8 qf1 = *(const bf16x8*)(Qp + (size_t)(16 + n16) * 32 + G * 8);

  f32x4 O00 = {0.f,0.f,0.f,0.f}, O01 = {0.f,0.f,0.f,0.f};
  f32x4 O10 = {0.f,0.f,0.f,0.f}, O11 = {0.f,0.f,0.f,0.f};
  float m0 = -3.0e38f, m1 = -3.0e38f, l0 = 0.f, l1 = 0.f;

  const u16* Kb = Kg + ((size_t)bh * 4096 + mh * 2048) * 32;
  const u16* Vb = Vtg + (size_t)bh * 32 * 4096 + mh * 2048;
  u32* Pw = Ps[w];

  for (int it = 0; it < 32; ++it) {
    const u16* Kt = Kb + (size_t)it * 64 * 32;
    bf16x8 kf0 = *(const bf16x8*)(Kt + (size_t)(n16) * 32 + G * 8);
    bf16x8 kf1 = *(const bf16x8*)(Kt + (size_t)(16 + n16) * 32 + G * 8);
    bf16x8 kf2 = *(const bf16x8*)(Kt + (size_t)(32 + n16) * 32 + G * 8);
    bf16x8 kf3 = *(const bf16x8*)(Kt + (size_t)(48 + n16) * 32 + G * 8);
    const f32x4 z = {0.f, 0.f, 0.f, 0.f};
    f32x4 S0[4], S1[4];
    S0[0] = MFMA(kf0, qf0, z);
    S0[1] = MFMA(kf1, qf0, z);
    S0[2] = MFMA(kf2, qf0, z);
    S0[3] = MFMA(kf3, qf0, z);
    S1[0] = MFMA(kf0, qf1, z);
    S1[1] = MFMA(kf1, qf1, z);
    S1[2] = MFMA(kf2, qf1, z);
    S1[3] = MFMA(kf3, qf1, z);

    float mt0 = fmaxf(fmaxf(S0[0].x, S0[0].y), fmaxf(S0[0].z, S0[0].w));
    float mt1 = fmaxf(fmaxf(S1[0].x, S1[0].y), fmaxf(S1[0].z, S1[0].w));
#pragma unroll
    for (int t = 1; t < 4; t++) {
      mt0 = fmaxf(mt0, fmaxf(fmaxf(S0[t].x, S0[t].y), fmaxf(S0[t].z, S0[t].w)));
      mt1 = fmaxf(mt1, fmaxf(fmaxf(S1[t].x, S1[t].y), fmaxf(S1[t].z, S1[t].w)));
    }
    mt0 = fmaxf(mt0, __shfl_xor(mt0, 16, 64));
    mt0 = fmaxf(mt0, __shfl_xor(mt0, 32, 64));
    mt1 = fmaxf(mt1, __shfl_xor(mt1, 16, 64));
    mt1 = fmaxf(mt1, __shfl_xor(mt1, 32, 64));
    float mn0 = fmaxf(m0, mt0), mn1 = fmaxf(m1, mt1);
    if (__any((mt0 > m0) | (mt1 > m1))) {
      float a0 = fexp2(m0 - mn0);
      float a1 = fexp2(m1 - mn1);
      l0 *= a0; l1 *= a1;
      O00 *= a0; O01 *= a0; O10 *= a1; O11 *= a1;
    }
    m0 = mn0; m1 = mn1;

    float rs0 = 0.f, rs1 = 0.f;
#pragma unroll
    for (int t = 0; t < 4; t++) {
      float p0 = fexp2(S0[t].x - m0);
      float p1 = fexp2(S0[t].y - m0);
      float p2 = fexp2(S0[t].z - m0);
      float p3 = fexp2(S0[t].w - m0);
      rs0 += (p0 + p1) + (p2 + p3);
      uint2 pr;
      pr.x = __builtin_amdgcn_perm(__float_as_uint(p1), __float_as_uint(p0), 0x07060302u);
      pr.y = __builtin_amdgcn_perm(__float_as_uint(p3), __float_as_uint(p2), 0x07060302u);
      *(uint2*)&Pw[n16 * 36 + 8 * t + 2 * G] = pr;
      float q0 = fexp2(S1[t].x - m1);
      float q1 = fexp2(S1[t].y - m1);
      float q2 = fexp2(S1[t].z - m1);
      float q3 = fexp2(S1[t].w - m1);
      rs1 += (q0 + q1) + (q2 + q3);
      uint2 qr;
      qr.x = __builtin_amdgcn_perm(__float_as_uint(q1), __float_as_uint(q0), 0x07060302u);
      qr.y = __builtin_amdgcn_perm(__float_as_uint(q3), __float_as_uint(q2), 0x07060302u);
      *(uint2*)&Pw[(16 + n16) * 36 + 8 * t + 2 * G] = qr;
    }
    rs0 += __shfl_xor(rs0, 16, 64);
    rs0 += __shfl_xor(rs0, 32, 64);
    rs1 += __shfl_xor(rs1, 16, 64);
    rs1 += __shfl_xor(rs1, 32, 64);
    l0 += rs0; l1 += rs1;

#pragma unroll
    for (int c = 0; c < 2; c++) {
      const u16* Vp = Vb + (size_t)it * 64 + c * 32 + G * 8;
      bf16x8 va0 = *(const bf16x8*)(Vp + (size_t)n16 * 4096);
      bf16x8 va1 = *(const bf16x8*)(Vp + (size_t)(16 + n16) * 4096);
      union { uint4 u; bf16x8 v; } B0, B1;
      B0.u = *(uint4*)&Pw[n16 * 36 + 16 * c + 4 * G];
      B1.u = *(uint4*)&Pw[(16 + n16) * 36 + 16 * c + 4 * G];
      O00 = MFMA(va0, B0.v, O00);
      O01 = MFMA(va1, B0.v, O01);
      O10 = MFMA(va0, B1.v, O10);
      O11 = MFMA(va1, B1.v, O11);
    }
  }

  if (mh == 1) {
    float* dst = &MX[g][lane][0];
    *(f32x4*)(dst + 0)  = O00;
    *(f32x4*)(dst + 4)  = O01;
    *(f32x4*)(dst + 8)  = O10;
    *(f32x4*)(dst + 12) = O11;
    dst[16] = m0; dst[17] = l0; dst[18] = m1; dst[19] = l1;
  }
  __syncthreads();
  if (mh == 0) {
    const float* src = &MX[g][lane][0];
    f32x4 P00 = *(const f32x4*)(src + 0);
    f32x4 P01 = *(const f32x4*)(src + 4);
    f32x4 P10 = *(const f32x4*)(src + 8);
    f32x4 P11 = *(const f32x4*)(src + 12);
    float pm0 = src[16], pl0 = src[17], pm1 = src[18], pl1 = src[19];

    float M0 = fmaxf(m0, pm0);
    float se0 = fexp2(m0 - M0), so0 = fexp2(pm0 - M0);
    float rl0 = 1.0f / (l0 * se0 + pl0 * so0);
    float M1 = fmaxf(m1, pm1);
    float se1 = fexp2(m1 - M1), so1 = fexp2(pm1 - M1);
    float rl1 = 1.0f / (l1 * se1 + pl1 * so1);
    const int s0 = b * 4096 + qbase + n16;
    const int s1 = s0 + 16;
    const int cb0 = h * 2, cb1 = h * 2 + 1;
    u16 pk[4];
#pragma unroll
    for (int r = 0; r < 4; r++) pk[r] = f2bf((O00[r] * se0 + P00[r] * so0) * rl0);
    *(uint2*)(attnT + ((size_t)cb0 * 8192 + s0) * 16 + G * 4) = *(uint2*)pk;
#pragma unroll
    for (int r = 0; r < 4; r++) pk[r] = f2bf((O01[r] * se0 + P01[r] * so0) * rl0);
    *(uint2*)(attnT + ((size_t)cb1 * 8192 + s0) * 16 + G * 4) = *(uint2*)pk;
#pragma unroll
    for (int r = 0; r < 4; r++) pk[r] = f2bf((O10[r] * se1 + P10[r] * so1) * rl1);
    *(uint2*)(attnT + ((size_t)cb0 * 8192 + s1) * 16 + G * 4) = *(uint2*)pk;
#pragma unroll
    for (int r = 0; r < 4; r++) pk[r] = f2bf((O11[r] * se1 + P11[r] * so1) * rl1);
    *(uint2*)(attnT + ((size_t)cb1 * 8192 + s1) * 16 + G * 4) = *(uint2*)pk;
  }
}

// ---------------------------------------------------------------------------
// proj MFMA + BN: out = BN(Wp @ attn + Wp @ local), two B-streams, one acc.
// grid (128 nB=64, 4 oB=64); wave = 32o x 32n. fp32 output [b][c][n].
// ---------------------------------------------------------------------------
__global__ __launch_bounds__(256, 4) void proj_mfma_kernel(
    const u16* __restrict__ attnT, const u16* __restrict__ localT,
    const u16* __restrict__ wprojb,
    const float* __restrict__ g, const float* __restrict__ be,
    const float* __restrict__ mu, const float* __restrict__ var,
    float* __restrict__ out) {
  const int nB = blockIdx.x * 64;
  const int oB = blockIdx.y * 64;
  const int tid = threadIdx.x, lane = tid & 63, wv = tid >> 6;
  const int n16 = lane & 15, G = lane >> 4;
  const int waveO = oB + (wv >> 1) * 32;
  const int waveN = nB + (wv & 1) * 32;
  f32x4 acc[2][2] = {};
  const u16* Ap = wprojb + (size_t)(waveO + n16) * 256 + G * 8;
  const size_t boff = ((size_t)(G >> 1) * 8192 + waveN + n16) * 16 + (G & 1) * 8;
  for (int c0 = 0; c0 < 256; c0 += 32) {
    bf16x8 a0 = *(const bf16x8*)(Ap + c0);
    bf16x8 a1 = *(const bf16x8*)(Ap + 16 * 256 + c0);
    const size_t bo = boff + (size_t)(c0 >> 4) * 131072;
    bf16x8 p0 = *(const bf16x8*)(attnT + bo);
    bf16x8 p1 = *(const bf16x8*)(attnT + bo + 256);
    bf16x8 q0 = *(const bf16x8*)(localT + bo);
    bf16x8 q1 = *(const bf16x8*)(localT + bo + 256);
    acc[0][0] = MFMA(a0, p0, acc[0][0]);
    acc[0][1] = MFMA(a0, p1, acc[0][1]);
    acc[1][0] = MFMA(a1, p0, acc[1][0]);
    acc[1][1] = MFMA(a1, p1, acc[1][1]);
    acc[0][0] = MFMA(a0, q0, acc[0][0]);
    acc[0][1] = MFMA(a0, q1, acc[0][1]);
    acc[1][0] = MFMA(a1, q0, acc[1][0]);
    acc[1][1] = MFMA(a1, q1, acc[1][1]);
  }
#pragma unroll
  for (int i = 0; i < 2; i++) {
    int o0 = waveO + i * 16 + G * 4;
    float inv[4], sh[4];
#pragma unroll
    for (int r = 0; r < 4; r++) {
      int o = o0 + r;
      float iv = g[o] * rsqrtf(var[o] + EPSV);
      inv[r] = iv; sh[r] = be[o] - mu[o] * iv;
    }
#pragma unroll
    for (int j = 0; j < 2; j++) {
      int s = waveN + j * 16 + n16;
      int b = s >> 12, n = s & 4095;
      float* op = out + ((size_t)(b * 256 + o0)) * 4096 + n;
#pragma unroll
      for (int r = 0; r < 4; r++) op[(size_t)r * 4096] = acc[i][j][r] * inv[r] + sh[r];
    }
  }
}

extern "C" void kernel_launch(void* const* d_in, const int* in_sizes, int n_in,
                              void* d_out, int out_size, void* d_ws, size_t ws_size,
                              hipStream_t stream) {
  (void)in_sizes; (void)n_in; (void)out_size; (void)ws_size;
  const float* x       = (const float*)d_in[0];
  const float* w_qkv   = (const float*)d_in[1];
  const float* w_local = (const float*)d_in[2];
  const float* lg = (const float*)d_in[3];
  const float* lb = (const float*)d_in[4];
  const float* lm = (const float*)d_in[5];
  const float* lv = (const float*)d_in[6];
  const float* w_proj  = (const float*)d_in[7];
  const float* pg = (const float*)d_in[8];
  const float* pb = (const float*)d_in[9];
  const float* pm = (const float*)d_in[10];
  const float* pvr = (const float*)d_in[11];
  float* out = (float*)d_out;

  // ws layout (u16 units)
  u16* Q      = (u16*)d_ws;          // 2M
  u16* K      = Q + 2097152;         // 2M
  u16* Vt     = K + 2097152;         // 2M
  u16* xT     = Vt + 2097152;        // 2M
  u16* attnT  = xT + 2097152;        // 2M
  u16* localT = attnT + 2097152;     // 2M
  u16* wqkvb  = localT + 2097152;    // 196608
  u16* wprojb = wqkvb + 196608;      // 65536
  u16* wb     = wprojb + 65536;      // 589824  (total ~26.9 MB)

  hipLaunchKernelGGL(prep_x_kernel, dim3(16, 16, 2), dim3(256), 0, stream, x, xT);
  hipLaunchKernelGGL(prep_w_kernel, dim3(1280), dim3(256), 0, stream,
                     w_qkv, w_proj, w_local, wqkvb, wprojb, wb);
  hipLaunchKernelGGL(qkv_mfma_kernel, dim3(64, 12), dim3(256), 0, stream,
                     xT, wqkvb, Q, K, Vt);
  hipLaunchKernelGGL(conv_mfma_kernel, dim3(128, 4), dim3(256), 0, stream,
                     xT, wb, lg, lb, lm, lv, localT);
  hipLaunchKernelGGL(flash_mfma_kernel, dim3(1024), dim3(256), 0, stream,
                     Q, K, Vt, attnT);
  hipLaunchKernelGGL(proj_mfma_kernel, dim3(128, 4), dim3(256), 0, stream,
                     attnT, localT, wprojb, pg, pb, pm, pvr, out);
}

// Round 7
// 236.179 us; speedup vs baseline: 10.5042x; 1.0127x over previous
//
#include <hip/hip_runtime.h>

#define EPSV 1e-5f

typedef unsigned short u16;
typedef unsigned int u32;
typedef __attribute__((ext_vector_type(8))) short bf16x8;
typedef __attribute__((ext_vector_type(4))) float f32x4;

__device__ __forceinline__ u16 f2bf(float f) {
  u32 u = __float_as_uint(f);
  u32 r = (u + 0x7FFFu + ((u >> 16) & 1u)) >> 16;
  return (u16)r;
}
__device__ __forceinline__ float fexp2(float x) {
  float r;
  asm("v_exp_f32 %0, %1" : "=v"(r) : "v"(x));
  return r;
}

#define MFMA(a, b, c) __builtin_amdgcn_mfma_f32_16x16x32_bf16((a), (b), (c), 0, 0, 0)

// ---------------------------------------------------------------------------
// prep (fused): blocks 0..511 transpose x -> xT bf16 [(c>>4)][s][c&15];
// blocks 512..1791 cast weights (QSCALE*log2e folded into Wq rows).
// ---------------------------------------------------------------------------
__global__ __launch_bounds__(256) void prep_kernel(
    const float* __restrict__ x, const float* __restrict__ wqkv,
    const float* __restrict__ wproj, const float* __restrict__ wloc,
    u16* __restrict__ xT, u16* __restrict__ wqkvb,
    u16* __restrict__ wprojb, u16* __restrict__ wb) {
  __shared__ float Ls[16][260];
  const int bid = blockIdx.x;
  const int tid = threadIdx.x;
  if (bid < 512) {
    const int nt = bid & 15, cb = (bid >> 4) & 15, b = bid >> 8;
    const int cc0 = tid >> 6, n4 = (tid & 63) * 4;
    const float* xb = x + ((size_t)(b * 256 + cb * 16)) * 4096 + nt * 256;
#pragma unroll
    for (int j = 0; j < 4; j++) {
      int cc = j * 4 + cc0;
      *(float4*)&Ls[cc][n4] = *(const float4*)(xb + (size_t)cc * 4096 + n4);
    }
    __syncthreads();
    const int n = tid;
    u16 buf[16];
#pragma unroll
    for (int c = 0; c < 16; c++) buf[c] = f2bf(Ls[c][n]);
    u16* dst = xT + ((size_t)cb * 8192 + b * 4096 + nt * 256 + n) * 16;
    *(uint4*)(dst) = *(uint4*)&buf[0];
    *(uint4*)(dst + 8) = *(uint4*)&buf[8];
  } else {
    const int r = bid - 512, c = tid;
    const float QSCALE = 0.17677669529663687f * 1.4426950408889634f;
    if (r < 768) {
      float sc = (r < 256) ? QSCALE : 1.0f;
      wqkvb[r * 256 + c] = f2bf(wqkv[r * 256 + c] * sc);
    } else if (r < 1024) {
      int o = r - 768;
      wprojb[o * 256 + c] = f2bf(wproj[o * 256 + c]);
    } else {
      int o = r - 1024;
      const float* src = wloc + ((size_t)o * 256 + c) * 9;
#pragma unroll
      for (int tap = 0; tap < 9; tap++)
        wb[tap * 65536 + o * 256 + c] = f2bf(src[tap]);
    }
  }
}

// ---------------------------------------------------------------------------
// qkvconv (fused): blocks 0..767 = qkv GEMM (wave 32o x 64n, block 64o x 128n),
// blocks 768..1279 = conv3x3+BN (wave 32o x 32n, block 64o x 64n).
// Both direct-from-L2, no LDS, no barriers.
// ---------------------------------------------------------------------------
__global__ __launch_bounds__(256, 4) void qkvconv_kernel(
    const u16* __restrict__ xT, const u16* __restrict__ wqkvb,
    const u16* __restrict__ wb,
    const float* __restrict__ g, const float* __restrict__ be,
    const float* __restrict__ mu, const float* __restrict__ var,
    u16* __restrict__ Qg, u16* __restrict__ Kg, u16* __restrict__ Vtg,
    u16* __restrict__ localT) {
  const int bid = blockIdx.x;
  const int tid = threadIdx.x, lane = tid & 63, wv = tid >> 6;
  const int n16 = lane & 15, G = lane >> 4;
  if (bid < 768) {
    // ---------------- qkv ----------------
    const int nB = (bid & 63) * 128;
    const int oB = (bid >> 6) * 64;
    const int waveO = oB + (wv >> 1) * 32;
    const int waveN = nB + (wv & 1) * 64;
    f32x4 acc[2][4] = {};
    const u16* Ap = wqkvb + (size_t)(waveO + n16) * 256 + G * 8;
    const u16* Bp = xT + ((size_t)(G >> 1) * 8192 + waveN + n16) * 16 + (G & 1) * 8;
    for (int c0 = 0; c0 < 256; c0 += 32) {
      bf16x8 a0 = *(const bf16x8*)(Ap + c0);
      bf16x8 a1 = *(const bf16x8*)(Ap + 16 * 256 + c0);
      const u16* bp = Bp + (size_t)(c0 >> 4) * 131072;
      bf16x8 b0 = *(const bf16x8*)(bp);
      bf16x8 b1 = *(const bf16x8*)(bp + 256);
      bf16x8 b2 = *(const bf16x8*)(bp + 512);
      bf16x8 b3 = *(const bf16x8*)(bp + 768);
      acc[0][0] = MFMA(a0, b0, acc[0][0]);
      acc[0][1] = MFMA(a0, b1, acc[0][1]);
      acc[0][2] = MFMA(a0, b2, acc[0][2]);
      acc[0][3] = MFMA(a0, b3, acc[0][3]);
      acc[1][0] = MFMA(a1, b0, acc[1][0]);
      acc[1][1] = MFMA(a1, b1, acc[1][1]);
      acc[1][2] = MFMA(a1, b2, acc[1][2]);
      acc[1][3] = MFMA(a1, b3, acc[1][3]);
    }
    const int which = oB >> 8;
    if (which < 2) {
      u16* base = which ? Kg : Qg;
#pragma unroll
      for (int i = 0; i < 2; i++) {
        int o0 = waveO + i * 16 + G * 4;
        int h = (o0 >> 5) & 7, d0 = o0 & 31;
#pragma unroll
        for (int j = 0; j < 4; j++) {
          int s = waveN + j * 16 + n16;
          int b = s >> 12, n = s & 4095;
          u16 pk[4];
#pragma unroll
          for (int r = 0; r < 4; r++) pk[r] = f2bf(acc[i][j][r]);
          *(uint2*)(base + ((size_t)(b * 8 + h) * 4096 + n) * 32 + d0) = *(uint2*)pk;
        }
      }
    } else {
#pragma unroll
      for (int i = 0; i < 2; i++) {
        int o0 = waveO + i * 16 + G * 4;
        int h = (o0 >> 5) & 7, d0 = o0 & 31;
#pragma unroll
        for (int j = 0; j < 4; j++) {
          int s = waveN + j * 16 + n16;
          int b = s >> 12, n = s & 4095;
          u16* vp = Vtg + ((size_t)(b * 8 + h) * 32 + d0) * 4096 + n;
#pragma unroll
          for (int r = 0; r < 4; r++) vp[(size_t)r * 4096] = f2bf(acc[i][j][r]);
        }
      }
    }
  } else {
    // ---------------- conv3x3 + BN ----------------
    const int r0 = bid - 768;
    const int nB = (r0 & 127) * 64;
    const int oB = (r0 >> 7) * 64;
    const int waveO = oB + (wv >> 1) * 32;
    const int waveN = nB + (wv & 1) * 32;
    const int y = (nB >> 6) & 63;
    const int x0 = waveN & 63;
    f32x4 acc[2][2] = {};
    const u16* Ap = wb + (size_t)(waveO + n16) * 256 + G * 8;
    const u16* Bp = xT + ((size_t)(G >> 1) * 8192 + waveN + n16) * 16 + (G & 1) * 8;
    const bf16x8 z = {0, 0, 0, 0, 0, 0, 0, 0};
    for (int c0 = 0; c0 < 256; c0 += 32) {
      const u16* bp = Bp + (size_t)(c0 >> 4) * 131072;
      const u16* ap = Ap + c0;
#pragma unroll
      for (int tap = 0; tap < 9; tap++) {
        const int dy = tap / 3 - 1, dx = tap % 3 - 1;
        int yy = y + dy;
        if ((unsigned)yy >= 64u) continue;
        bf16x8 a0 = *(const bf16x8*)(ap + (size_t)tap * 65536);
        bf16x8 a1 = *(const bf16x8*)(ap + (size_t)tap * 65536 + 16 * 256);
        const int off = dy * 64 + dx;
        bf16x8 b0, b1;
        if (dx == 0) {
          b0 = *(const bf16x8*)(bp + (ptrdiff_t)off * 16);
          b1 = *(const bf16x8*)(bp + (ptrdiff_t)(off + 16) * 16);
        } else {
          bool v0 = (unsigned)(x0 + n16 + dx) < 64u;
          bool v1 = (unsigned)(x0 + 16 + n16 + dx) < 64u;
          int o0 = v0 ? off : 0;
          int o1 = v1 ? (off + 16) : 16;
          bf16x8 t0 = *(const bf16x8*)(bp + (ptrdiff_t)o0 * 16);
          bf16x8 t1 = *(const bf16x8*)(bp + (ptrdiff_t)o1 * 16);
          b0 = v0 ? t0 : z;
          b1 = v1 ? t1 : z;
        }
        acc[0][0] = MFMA(a0, b0, acc[0][0]);
        acc[0][1] = MFMA(a0, b1, acc[0][1]);
        acc[1][0] = MFMA(a1, b0, acc[1][0]);
        acc[1][1] = MFMA(a1, b1, acc[1][1]);
      }
    }
#pragma unroll
    for (int i = 0; i < 2; i++) {
      int o0 = waveO + i * 16 + G * 4;
      float inv[4], sh[4];
#pragma unroll
      for (int r = 0; r < 4; r++) {
        int o = o0 + r;
        float iv = g[o] * rsqrtf(var[o] + EPSV);
        inv[r] = iv; sh[r] = be[o] - mu[o] * iv;
      }
#pragma unroll
      for (int j = 0; j < 2; j++) {
        int s = waveN + j * 16 + n16;
        u16 pk[4];
#pragma unroll
        for (int r = 0; r < 4; r++) pk[r] = f2bf(acc[i][j][r] * inv[r] + sh[r]);
        *(uint2*)(localT + ((size_t)(o0 >> 4) * 8192 + s) * 16 + (o0 & 15)) = *(uint2*)pk;
      }
    }
  }
}

// ---------------------------------------------------------------------------
// flash attention: R5-proven max-tracked softmax (__any-skipped rescale),
// plus safe deltas: K-tile prefetch and deferred per-lane l partials
// (valid because m/alpha stay column-uniform via the per-iter max reduce).
// ---------------------------------------------------------------------------
__global__ __launch_bounds__(256, 4) void flash_mfma_kernel(
    const u16* __restrict__ Qg, const u16* __restrict__ Kg,
    const u16* __restrict__ Vtg, u16* __restrict__ attnT) {
  __shared__ u32 Ps[4][32 * 36];
  __shared__ float MX[2][64][20];
  const int bid = blockIdx.x;
  const int bh = bid >> 6, qt = bid & 63;
  const int tid = threadIdx.x, lane = tid & 63, w = tid >> 6;
  const int n16 = lane & 15, G = lane >> 4;
  const int g = w >> 1, mh = w & 1;
  const int b = bh >> 3, h = bh & 7;
  const int qbase = qt * 64 + g * 32;

  const u16* Qp = Qg + ((size_t)bh * 4096 + qbase) * 32;
  const bf16x8 qf0 = *(const bf16x8*)(Qp + (size_t)n16 * 32 + G * 8);
  const bf16x8 qf1 = *(const bf16x8*)(Qp + (size_t)(16 + n16) * 32 + G * 8);

  f32x4 O00 = {0.f,0.f,0.f,0.f}, O01 = {0.f,0.f,0.f,0.f};
  f32x4 O10 = {0.f,0.f,0.f,0.f}, O11 = {0.f,0.f,0.f,0.f};
  float m0 = -3.0e38f, m1 = -3.0e38f, l0 = 0.f, l1 = 0.f;  // l = per-lane partial

  const u16* Kb = Kg + ((size_t)bh * 4096 + mh * 2048) * 32;
  const u16* Vb = Vtg + (size_t)bh * 32 * 4096 + mh * 2048;
  u32* Pw = Ps[w];

  bf16x8 kf0 = *(const bf16x8*)(Kb + (size_t)n16 * 32 + G * 8);
  bf16x8 kf1 = *(const bf16x8*)(Kb + (size_t)(16 + n16) * 32 + G * 8);
  bf16x8 kf2 = *(const bf16x8*)(Kb + (size_t)(32 + n16) * 32 + G * 8);
  bf16x8 kf3 = *(const bf16x8*)(Kb + (size_t)(48 + n16) * 32 + G * 8);

  for (int it = 0; it < 32; ++it) {
    const f32x4 z = {0.f, 0.f, 0.f, 0.f};
    f32x4 S0[4], S1[4];
    S0[0] = MFMA(kf0, qf0, z); S1[0] = MFMA(kf0, qf1, z);
    S0[1] = MFMA(kf1, qf0, z); S1[1] = MFMA(kf1, qf1, z);
    S0[2] = MFMA(kf2, qf0, z); S1[2] = MFMA(kf2, qf1, z);
    S0[3] = MFMA(kf3, qf0, z); S1[3] = MFMA(kf3, qf1, z);

    // prefetch next K-tile (wrap reload at end is harmless)
    {
      const u16* Kn = Kb + (size_t)(((it + 1) & 31) * 64) * 32;
      kf0 = *(const bf16x8*)(Kn + (size_t)n16 * 32 + G * 8);
      kf1 = *(const bf16x8*)(Kn + (size_t)(16 + n16) * 32 + G * 8);
      kf2 = *(const bf16x8*)(Kn + (size_t)(32 + n16) * 32 + G * 8);
      kf3 = *(const bf16x8*)(Kn + (size_t)(48 + n16) * 32 + G * 8);
    }

    float mt0 = fmaxf(fmaxf(S0[0].x, S0[0].y), fmaxf(S0[0].z, S0[0].w));
    float mt1 = fmaxf(fmaxf(S1[0].x, S1[0].y), fmaxf(S1[0].z, S1[0].w));
#pragma unroll
    for (int t = 1; t < 4; t++) {
      mt0 = fmaxf(mt0, fmaxf(fmaxf(S0[t].x, S0[t].y), fmaxf(S0[t].z, S0[t].w)));
      mt1 = fmaxf(mt1, fmaxf(fmaxf(S1[t].x, S1[t].y), fmaxf(S1[t].z, S1[t].w)));
    }
    mt0 = fmaxf(mt0, __shfl_xor(mt0, 16, 64));
    mt0 = fmaxf(mt0, __shfl_xor(mt0, 32, 64));
    mt1 = fmaxf(mt1, __shfl_xor(mt1, 16, 64));
    mt1 = fmaxf(mt1, __shfl_xor(mt1, 32, 64));
    float mn0 = fmaxf(m0, mt0), mn1 = fmaxf(m1, mt1);
    if (__any((mt0 > m0) | (mt1 > m1))) {
      float a0 = fexp2(m0 - mn0);
      float a1 = fexp2(m1 - mn1);
      l0 *= a0; l1 *= a1;
      O00 *= a0; O01 *= a0; O10 *= a1; O11 *= a1;
    }
    m0 = mn0; m1 = mn1;

    // P = exp2(S - m): per-lane l partials; pack (truncating) -> wave LDS
#pragma unroll
    for (int t = 0; t < 4; t++) {
      float p0 = fexp2(S0[t].x - m0), p1 = fexp2(S0[t].y - m0);
      float p2 = fexp2(S0[t].z - m0), p3 = fexp2(S0[t].w - m0);
      l0 += (p0 + p1) + (p2 + p3);
      uint2 pr;
      pr.x = __builtin_amdgcn_perm(__float_as_uint(p1), __float_as_uint(p0), 0x07060302u);
      pr.y = __builtin_amdgcn_perm(__float_as_uint(p3), __float_as_uint(p2), 0x07060302u);
      *(uint2*)&Pw[n16 * 36 + 8 * t + 2 * G] = pr;
      float q0 = fexp2(S1[t].x - m1), q1 = fexp2(S1[t].y - m1);
      float q2 = fexp2(S1[t].z - m1), q3 = fexp2(S1[t].w - m1);
      l1 += (q0 + q1) + (q2 + q3);
      uint2 qr;
      qr.x = __builtin_amdgcn_perm(__float_as_uint(q1), __float_as_uint(q0), 0x07060302u);
      qr.y = __builtin_amdgcn_perm(__float_as_uint(q3), __float_as_uint(q2), 0x07060302u);
      *(uint2*)&Pw[(16 + n16) * 36 + 8 * t + 2 * G] = qr;
    }

    // O^T += V^T . P^T
#pragma unroll
    for (int c = 0; c < 2; c++) {
      const u16* Vp = Vb + (size_t)it * 64 + c * 32 + G * 8;
      bf16x8 va0 = *(const bf16x8*)(Vp + (size_t)n16 * 4096);
      bf16x8 va1 = *(const bf16x8*)(Vp + (size_t)(16 + n16) * 4096);
      union { uint4 u; bf16x8 v; } B0, B1;
      B0.u = *(uint4*)&Pw[n16 * 36 + 16 * c + 4 * G];
      B1.u = *(uint4*)&Pw[(16 + n16) * 36 + 16 * c + 4 * G];
      O00 = MFMA(va0, B0.v, O00);
      O01 = MFMA(va1, B0.v, O01);
      O10 = MFMA(va0, B1.v, O10);
      O11 = MFMA(va1, B1.v, O11);
    }
  }

  // merge m-split pairs (waves 2g / 2g+1) and store
  if (mh == 1) {
    float* dst = &MX[g][lane][0];
    *(f32x4*)(dst + 0)  = O00;
    *(f32x4*)(dst + 4)  = O01;
    *(f32x4*)(dst + 8)  = O10;
    *(f32x4*)(dst + 12) = O11;
    dst[16] = m0; dst[17] = l0; dst[18] = m1; dst[19] = l1;
  }
  __syncthreads();
  if (mh == 0) {
    const float* src = &MX[g][lane][0];
    f32x4 P00 = *(const f32x4*)(src + 0);
    f32x4 P01 = *(const f32x4*)(src + 4);
    f32x4 P10 = *(const f32x4*)(src + 8);
    f32x4 P11 = *(const f32x4*)(src + 12);
    float pm0 = src[16], pl0 = src[17], pm1 = src[18], pl1 = src[19];

    float M0 = fmaxf(m0, pm0);
    float se0 = fexp2(m0 - M0), so0 = fexp2(pm0 - M0);
    float M1 = fmaxf(m1, pm1);
    float se1 = fexp2(m1 - M1), so1 = fexp2(pm1 - M1);
    // combined per-lane l partials, then reduce across G-lane groups
    float ls0 = l0 * se0 + pl0 * so0;
    float ls1 = l1 * se1 + pl1 * so1;
    ls0 += __shfl_xor(ls0, 16, 64);
    ls0 += __shfl_xor(ls0, 32, 64);
    ls1 += __shfl_xor(ls1, 16, 64);
    ls1 += __shfl_xor(ls1, 32, 64);
    const float rl0 = 1.0f / ls0, rl1 = 1.0f / ls1;

    const int s0 = b * 4096 + qbase + n16;
    const int s1 = s0 + 16;
    const int cb0 = h * 2, cb1 = h * 2 + 1;
    u16 pk[4];
#pragma unroll
    for (int r = 0; r < 4; r++) pk[r] = f2bf((O00[r] * se0 + P00[r] * so0) * rl0);
    *(uint2*)(attnT + ((size_t)cb0 * 8192 + s0) * 16 + G * 4) = *(uint2*)pk;
#pragma unroll
    for (int r = 0; r < 4; r++) pk[r] = f2bf((O01[r] * se0 + P01[r] * so0) * rl0);
    *(uint2*)(attnT + ((size_t)cb1 * 8192 + s0) * 16 + G * 4) = *(uint2*)pk;
#pragma unroll
    for (int r = 0; r < 4; r++) pk[r] = f2bf((O10[r] * se1 + P10[r] * so1) * rl1);
    *(uint2*)(attnT + ((size_t)cb0 * 8192 + s1) * 16 + G * 4) = *(uint2*)pk;
#pragma unroll
    for (int r = 0; r < 4; r++) pk[r] = f2bf((O11[r] * se1 + P11[r] * so1) * rl1);
    *(uint2*)(attnT + ((size_t)cb1 * 8192 + s1) * 16 + G * 4) = *(uint2*)pk;
  }
}

// ---------------------------------------------------------------------------
// proj MFMA + BN: out = BN(Wp @ attn + Wp @ local), two B-streams, one acc.
// ---------------------------------------------------------------------------
__global__ __launch_bounds__(256, 4) void proj_mfma_kernel(
    const u16* __restrict__ attnT, const u16* __restrict__ localT,
    const u16* __restrict__ wprojb,
    const float* __restrict__ g, const float* __restrict__ be,
    const float* __restrict__ mu, const float* __restrict__ var,
    float* __restrict__ out) {
  const int nB = blockIdx.x * 64;
  const int oB = blockIdx.y * 64;
  const int tid = threadIdx.x, lane = tid & 63, wv = tid >> 6;
  const int n16 = lane & 15, G = lane >> 4;
  const int waveO = oB + (wv >> 1) * 32;
  const int waveN = nB + (wv & 1) * 32;
  f32x4 acc[2][2] = {};
  const u16* Ap = wprojb + (size_t)(waveO + n16) * 256 + G * 8;
  const size_t boff = ((size_t)(G >> 1) * 8192 + waveN + n16) * 16 + (G & 1) * 8;
  for (int c0 = 0; c0 < 256; c0 += 32) {
    bf16x8 a0 = *(const bf16x8*)(Ap + c0);
    bf16x8 a1 = *(const bf16x8*)(Ap + 16 * 256 + c0);
    const size_t bo = boff + (size_t)(c0 >> 4) * 131072;
    bf16x8 p0 = *(const bf16x8*)(attnT + bo);
    bf16x8 p1 = *(const bf16x8*)(attnT + bo + 256);
    bf16x8 q0 = *(const bf16x8*)(localT + bo);
    bf16x8 q1 = *(const bf16x8*)(localT + bo + 256);
    acc[0][0] = MFMA(a0, p0, acc[0][0]);
    acc[0][1] = MFMA(a0, p1, acc[0][1]);
    acc[1][0] = MFMA(a1, p0, acc[1][0]);
    acc[1][1] = MFMA(a1, p1, acc[1][1]);
    acc[0][0] = MFMA(a0, q0, acc[0][0]);
    acc[0][1] = MFMA(a0, q1, acc[0][1]);
    acc[1][0] = MFMA(a1, q0, acc[1][0]);
    acc[1][1] = MFMA(a1, q1, acc[1][1]);
  }
#pragma unroll
  for (int i = 0; i < 2; i++) {
    int o0 = waveO + i * 16 + G * 4;
    float inv[4], sh[4];
#pragma unroll
    for (int r = 0; r < 4; r++) {
      int o = o0 + r;
      float iv = g[o] * rsqrtf(var[o] + EPSV);
      inv[r] = iv; sh[r] = be[o] - mu[o] * iv;
    }
#pragma unroll
    for (int j = 0; j < 2; j++) {
      int s = waveN + j * 16 + n16;
      int b = s >> 12, n = s & 4095;
      float* op = out + ((size_t)(b * 256 + o0)) * 4096 + n;
#pragma unroll
      for (int r = 0; r < 4; r++) op[(size_t)r * 4096] = acc[i][j][r] * inv[r] + sh[r];
    }
  }
}

extern "C" void kernel_launch(void* const* d_in, const int* in_sizes, int n_in,
                              void* d_out, int out_size, void* d_ws, size_t ws_size,
                              hipStream_t stream) {
  (void)in_sizes; (void)n_in; (void)out_size; (void)ws_size;
  const float* x       = (const float*)d_in[0];
  const float* w_qkv   = (const float*)d_in[1];
  const float* w_local = (const float*)d_in[2];
  const float* lg = (const float*)d_in[3];
  const float* lb = (const float*)d_in[4];
  const float* lm = (const float*)d_in[5];
  const float* lv = (const float*)d_in[6];
  const float* w_proj  = (const float*)d_in[7];
  const float* pg = (const float*)d_in[8];
  const float* pb = (const float*)d_in[9];
  const float* pm = (const float*)d_in[10];
  const float* pvr = (const float*)d_in[11];
  float* out = (float*)d_out;

  // ws layout (u16 units)
  u16* Q      = (u16*)d_ws;          // 2M
  u16* K      = Q + 2097152;         // 2M
  u16* Vt     = K + 2097152;         // 2M
  u16* xT     = Vt + 2097152;        // 2M
  u16* attnT  = xT + 2097152;        // 2M
  u16* localT = attnT + 2097152;     // 2M
  u16* wqkvb  = localT + 2097152;    // 196608
  u16* wprojb = wqkvb + 196608;      // 65536
  u16* wb     = wprojb + 65536;      // 589824

  hipLaunchKernelGGL(prep_kernel, dim3(1792), dim3(256), 0, stream,
                     x, w_qkv, w_proj, w_local, xT, wqkvb, wprojb, wb);
  hipLaunchKernelGGL(qkvconv_kernel, dim3(1280), dim3(256), 0, stream,
                     xT, wqkvb, wb, lg, lb, lm, lv, Q, K, Vt, localT);
  hipLaunchKernelGGL(flash_mfma_kernel, dim3(1024), dim3(256), 0, stream,
                     Q, K, Vt, attnT);
  hipLaunchKernelGGL(proj_mfma_kernel, dim3(128, 4), dim3(256), 0, stream,
                     attnT, localT, wprojb, pg, pb, pm, pvr, out);
}